// Round 1
// baseline (563.985 us; speedup 1.0000x reference)
//
#include <hip/hip_runtime.h>
#include <hip/hip_bf16.h>
#include <math.h>

#define NN 40000
#define EE 640000
#define HBITS 21
#define HSLOTS (1u << HBITS)
#define HMASK (HSLOTS - 1u)

// ---------------------------------------------------------------------------
// Pass 1 over edges: in-degree counts + hash-insert key = src*n + dst
// ---------------------------------------------------------------------------
__global__ __launch_bounds__(256) void edge_pass1(
    const int* __restrict__ src, const int* __restrict__ dst,
    int* __restrict__ cnt, unsigned* __restrict__ hk, unsigned* __restrict__ hc,
    int E, unsigned n) {
  int e = blockIdx.x * 256 + threadIdx.x;
  if (e >= E) return;
  int s = src[e], d = dst[e];
  atomicAdd(&cnt[d], 1);
  unsigned key = (unsigned)s * n + (unsigned)d;
  unsigned h = key * 2654435761u;
  h ^= h >> 16;
  unsigned idx = h & HMASK;
  unsigned tag = key + 1u;
  while (true) {
    unsigned old = atomicCAS(&hk[idx], 0u, tag);
    if (old == 0u || old == tag) {
      atomicAdd(&hc[idx], 1u);
      break;
    }
    idx = (idx + 1u) & HMASK;
  }
}

// ---------------------------------------------------------------------------
// dis[i] = rsqrt(indeg + 1)
// ---------------------------------------------------------------------------
__global__ __launch_bounds__(256) void dis_kernel(const int* __restrict__ cnt,
                                                  float* __restrict__ dis) {
  int i = blockIdx.x * 256 + threadIdx.x;
  if (i < NN) dis[i] = rsqrtf((float)(cnt[i] + 1));
}

// ---------------------------------------------------------------------------
// Single-block exclusive scan of cnt -> row_off (two-level, 256 threads)
// ---------------------------------------------------------------------------
__global__ __launch_bounds__(256) void scan_kernel(const int* __restrict__ cnt,
                                                   int* __restrict__ row_off) {
  __shared__ int part[256];
  int t = threadIdx.x;
  const int per = (NN + 255) / 256;  // 157
  int beg = t * per;
  int end = beg + per;
  if (end > NN) end = NN;
  int s = 0;
  for (int i = beg; i < end; i++) s += cnt[i];
  part[t] = s;
  __syncthreads();
  for (int off = 1; off < 256; off <<= 1) {
    int add = (t >= off) ? part[t - off] : 0;
    __syncthreads();
    part[t] += add;
    __syncthreads();
  }
  int base = part[t] - s;  // exclusive prefix of this thread's range
  int run = base;
  for (int i = beg; i < end; i++) {
    row_off[i] = run;
    run += cnt[i];
  }
  if (t == 255) row_off[NN] = run;
}

// ---------------------------------------------------------------------------
// CSR fill: csr_src / csr_w (= dis[src]) per incoming edge of each node
// ---------------------------------------------------------------------------
__global__ __launch_bounds__(256) void fill_kernel(
    const int* __restrict__ src, const int* __restrict__ dst,
    const int* __restrict__ row_off, int* __restrict__ cursor,
    const float* __restrict__ dis, int* __restrict__ csr_src,
    float* __restrict__ csr_w, int E) {
  int e = blockIdx.x * 256 + threadIdx.x;
  if (e >= E) return;
  int s = src[e], d = dst[e];
  int p = atomicAdd(&cursor[d], 1);
  int idx = row_off[d] + p;
  csr_src[idx] = s;
  csr_w[idx] = dis[s];
}

// ---------------------------------------------------------------------------
// reg_loss: per-edge reverse-key lookup, reduce, atomicAdd into out scalar
// ---------------------------------------------------------------------------
__global__ __launch_bounds__(256) void reg_lookup(
    const int* __restrict__ src, const int* __restrict__ dst,
    const unsigned* __restrict__ hk, const unsigned* __restrict__ hc,
    float* __restrict__ out_scalar, int E, unsigned n) {
  int e = blockIdx.x * 256 + threadIdx.x;
  unsigned cv = 0;
  if (e < E) {
    unsigned key = (unsigned)dst[e] * n + (unsigned)src[e];
    unsigned h = key * 2654435761u;
    h ^= h >> 16;
    unsigned idx = h & HMASK;
    unsigned tag = key + 1u;
    while (true) {
      unsigned kk = hk[idx];
      if (kk == 0u) break;
      if (kk == tag) {
        cv = hc[idx];
        break;
      }
      idx = (idx + 1u) & HMASK;
    }
  }
  float v = (float)cv;
  for (int off = 32; off; off >>= 1) v += __shfl_down(v, off, 64);
  __shared__ float ws[4];
  int lane = threadIdx.x & 63, w = threadIdx.x >> 6;
  if (lane == 0) ws[w] = v;
  __syncthreads();
  if (threadIdx.x == 0) atomicAdd(out_scalar, ws[0] + ws[1] + ws[2] + ws[3]);
}

// ---------------------------------------------------------------------------
// 128-wide normalized aggregation: out[i] = dis[i]*(sum_e dis[src]*H[src] + dis[i]*H[i])
// one wave per node; lane holds 2 columns as float2
// ---------------------------------------------------------------------------
__global__ __launch_bounds__(256) void agg128(
    const float* __restrict__ H, const float* __restrict__ dis,
    const int* __restrict__ row_off, const int* __restrict__ csr_src,
    const float* __restrict__ csr_w, float* __restrict__ out) {
  int node = blockIdx.x * 4 + (threadIdx.x >> 6);
  node = __builtin_amdgcn_readfirstlane(node);
  int lane = threadIdx.x & 63;
  float di = dis[node];
  const float2* hrow = (const float2*)(H + (size_t)node * 128);
  float2 v = hrow[lane];
  float a0 = di * v.x, a1 = di * v.y;
  int beg = row_off[node], end = row_off[node + 1];
  for (int e = beg; e < end; e++) {
    int s = csr_src[e];
    float w = csr_w[e];
    const float2* hs = (const float2*)(H + (size_t)s * 128);
    float2 u = hs[lane];
    a0 += w * u.x;
    a1 += w * u.y;
  }
  float2 o;
  o.x = di * a0;
  o.y = di * a1;
  ((float2*)(out + (size_t)node * 128))[lane] = o;
}

// ---------------------------------------------------------------------------
// fp32 GEMM: out[M x 128] = A[M x 128] @ W[128 x 128] + b (opt relu)
// 64-row tiles, K-tiles of 64; XT (transposed) + W tile in LDS; 8x4 per thread
// ---------------------------------------------------------------------------
__global__ __launch_bounds__(256) void gemm128(
    const float* __restrict__ A, const float* __restrict__ W,
    const float* __restrict__ bias, float* __restrict__ out, int relu) {
  __shared__ float XT[64][68];    // [k][row]
  __shared__ float Ws[64][128];   // [k][col]
  int t = threadIdx.x;
  int tx = t & 31, ty = t >> 5;
  int rowBase = blockIdx.x * 64;
  float acc[8][4] = {};
  for (int kt = 0; kt < 128; kt += 64) {
    {
      int kk = (t & 15) * 4;
      int r0 = t >> 4;
      for (int i = 0; i < 4; i++) {
        int r = r0 + i * 16;
        float4 v = *(const float4*)&A[(size_t)(rowBase + r) * 128 + kt + kk];
        XT[kk + 0][r] = v.x;
        XT[kk + 1][r] = v.y;
        XT[kk + 2][r] = v.z;
        XT[kk + 3][r] = v.w;
      }
    }
    {
      int c4 = (t & 31) * 4;
      int kr = t >> 5;
      for (int i = 0; i < 8; i++) {
        int k = kr + i * 8;
        *(float4*)&Ws[k][c4] = *(const float4*)&W[(size_t)(kt + k) * 128 + c4];
      }
    }
    __syncthreads();
#pragma unroll 8
    for (int k = 0; k < 64; k++) {
      float a[8];
      *(float4*)&a[0] = *(const float4*)&XT[k][ty * 8];
      *(float4*)&a[4] = *(const float4*)&XT[k][ty * 8 + 4];
      float4 b = *(const float4*)&Ws[k][tx * 4];
#pragma unroll
      for (int i = 0; i < 8; i++) {
        acc[i][0] += a[i] * b.x;
        acc[i][1] += a[i] * b.y;
        acc[i][2] += a[i] * b.z;
        acc[i][3] += a[i] * b.w;
      }
    }
    __syncthreads();
  }
  float4 bv = *(const float4*)&bias[tx * 4];
  for (int i = 0; i < 8; i++) {
    int r = rowBase + ty * 8 + i;
    float4 o;
    o.x = acc[i][0] + bv.x;
    o.y = acc[i][1] + bv.y;
    o.z = acc[i][2] + bv.z;
    o.w = acc[i][3] + bv.w;
    if (relu) {
      o.x = fmaxf(o.x, 0.f);
      o.y = fmaxf(o.y, 0.f);
      o.z = fmaxf(o.z, 0.f);
      o.w = fmaxf(o.w, 0.f);
    }
    *(float4*)&out[(size_t)r * 128 + tx * 4] = o;
  }
}

// ---------------------------------------------------------------------------
// GEMM 128 -> 40 (no bias): one wave per row, W3 in LDS
// ---------------------------------------------------------------------------
__global__ __launch_bounds__(256) void gemm40(const float* __restrict__ A,
                                              const float* __restrict__ W3,
                                              float* __restrict__ G) {
  __shared__ float Ws[128 * 40];
  int t = threadIdx.x;
  for (int i = t; i < 128 * 40; i += 256) Ws[i] = W3[i];
  __syncthreads();
  int node = __builtin_amdgcn_readfirstlane(blockIdx.x * 4 + (t >> 6));
  int lane = t & 63;
  int cl = lane < 40 ? lane : 39;
  const float* arow = A + (size_t)node * 128;
  float acc = 0.f;
#pragma unroll 8
  for (int k = 0; k < 128; k++) acc += arow[k] * Ws[k * 40 + cl];
  if (lane < 40) G[(size_t)node * 40 + lane] = acc;
}

// ---------------------------------------------------------------------------
// fused: 40-wide aggregation + bias + log_softmax -> d_out
// ---------------------------------------------------------------------------
__global__ __launch_bounds__(256) void agg40_softmax(
    const float* __restrict__ G, const float* __restrict__ dis,
    const int* __restrict__ row_off, const int* __restrict__ csr_src,
    const float* __restrict__ csr_w, const float* __restrict__ b3,
    float* __restrict__ outp) {
  int node = __builtin_amdgcn_readfirstlane(blockIdx.x * 4 + (threadIdx.x >> 6));
  int lane = threadIdx.x & 63;
  int cl = lane < 40 ? lane : 39;
  float di = dis[node];
  float a = di * G[(size_t)node * 40 + cl];
  int beg = row_off[node], end = row_off[node + 1];
  for (int e = beg; e < end; e++) {
    int s = csr_src[e];
    float w = csr_w[e];
    a += w * G[(size_t)s * 40 + cl];
  }
  float o = di * a + b3[cl];
  float m = (lane < 40) ? o : -1e30f;
  for (int off = 32; off; off >>= 1) m = fmaxf(m, __shfl_xor(m, off, 64));
  float ex = (lane < 40) ? expf(o - m) : 0.f;
  float ssum = ex;
  for (int off = 32; off; off >>= 1) ssum += __shfl_xor(ssum, off, 64);
  float res = o - m - logf(ssum);
  if (lane < 40) outp[(size_t)node * 40 + lane] = res;
}

// ---------------------------------------------------------------------------
extern "C" void kernel_launch(void* const* d_in, const int* in_sizes, int n_in,
                              void* d_out, int out_size, void* d_ws,
                              size_t ws_size, hipStream_t stream) {
  const float* X = (const float*)d_in[0];
  const int* ei = (const int*)d_in[1];
  const float* W1 = (const float*)d_in[2];
  const float* b1 = (const float*)d_in[3];
  const float* W2 = (const float*)d_in[4];
  const float* b2 = (const float*)d_in[5];
  const float* W3 = (const float*)d_in[6];
  const float* b3 = (const float*)d_in[7];
  float* out = (float*)d_out;

  const int n = NN;
  const int E = EE;
  const int* src = ei;
  const int* dst = ei + E;

  // workspace carve-up (256B aligned)
  char* w = (char*)d_ws;
  auto carve = [&](size_t bytes) {
    char* p = w;
    w += (bytes + 255) & ~(size_t)255;
    return p;
  };
  int* cnt = (int*)carve(NN * 4);
  float* dis = (float*)carve(NN * 4);
  int* row_off = (int*)carve((NN + 1) * 4);
  int* cursor = (int*)carve(NN * 4);
  int* csr_src = (int*)carve((size_t)EE * 4);
  float* csr_w = (float*)carve((size_t)EE * 4);
  unsigned* hk = (unsigned*)carve((size_t)HSLOTS * 4);
  unsigned* hc = (unsigned*)carve((size_t)HSLOTS * 4);
  float* B_agg = (float*)carve((size_t)NN * 128 * 4);
  float* B_h = (float*)carve((size_t)NN * 128 * 4);
  float* G3 = B_agg;  // reuse: B_agg is dead by the time G3 is produced

  // zero what needs zeroing
  hipMemsetAsync(cnt, 0, NN * 4, stream);
  hipMemsetAsync(cursor, 0, NN * 4, stream);
  hipMemsetAsync(hk, 0, (size_t)HSLOTS * 4, stream);
  hipMemsetAsync(hc, 0, (size_t)HSLOTS * 4, stream);
  hipMemsetAsync((char*)d_out + (size_t)NN * 40 * 4, 0, 4, stream);

  const int EB = (EE + 255) / 256;   // 2500
  const int NB = (NN + 255) / 256;   // 157
  const int WB = NN / 4;             // 10000 (wave-per-node kernels)

  edge_pass1<<<EB, 256, 0, stream>>>(src, dst, cnt, hk, hc, E, (unsigned)n);
  dis_kernel<<<NB, 256, 0, stream>>>(cnt, dis);
  scan_kernel<<<1, 256, 0, stream>>>(cnt, row_off);
  fill_kernel<<<EB, 256, 0, stream>>>(src, dst, row_off, cursor, dis, csr_src,
                                      csr_w, E);
  reg_lookup<<<EB, 256, 0, stream>>>(src, dst, hk, hc,
                                     out + (size_t)NN * 40, E, (unsigned)n);

  // layer 1: agg(X) -> B_agg ; gemm+relu -> B_h
  agg128<<<WB, 256, 0, stream>>>(X, dis, row_off, csr_src, csr_w, B_agg);
  gemm128<<<NN / 64, 256, 0, stream>>>(B_agg, W1, b1, B_h, 1);
  // layer 2: agg(B_h) -> B_agg ; gemm+relu -> B_h
  agg128<<<WB, 256, 0, stream>>>(B_h, dis, row_off, csr_src, csr_w, B_agg);
  gemm128<<<NN / 64, 256, 0, stream>>>(B_agg, W2, b2, B_h, 1);
  // layer 3: gemm40(B_h) -> G3 ; fused agg + bias + log_softmax -> out
  gemm40<<<WB, 256, 0, stream>>>(B_h, W3, G3);
  agg40_softmax<<<WB, 256, 0, stream>>>(G3, dis, row_off, csr_src, csr_w, b3,
                                        out);
}

// Round 2
// 475.790 us; speedup vs baseline: 1.1854x; 1.1854x over previous
//
#include <hip/hip_runtime.h>
#include <hip/hip_bf16.h>
#include <math.h>

#define NN 40000
#define EE 640000

// ---------------------------------------------------------------------------
// Pass 1 over edges: in-degree counts only (atomic throughput bound — keep
// it to exactly one atomic per edge; the old hash insert tripled the
// memory-side atomic traffic and cost 94us).
// ---------------------------------------------------------------------------
__global__ __launch_bounds__(256) void edge_pass1(
    const int* __restrict__ dst, int* __restrict__ cnt, int E) {
  int e = blockIdx.x * 256 + threadIdx.x;
  if (e >= E) return;
  atomicAdd(&cnt[dst[e]], 1);
}

// ---------------------------------------------------------------------------
// dis[i] = rsqrt(indeg + 1)
// ---------------------------------------------------------------------------
__global__ __launch_bounds__(256) void dis_kernel(const int* __restrict__ cnt,
                                                  float* __restrict__ dis) {
  int i = blockIdx.x * 256 + threadIdx.x;
  if (i < NN) dis[i] = rsqrtf((float)(cnt[i] + 1));
}

// ---------------------------------------------------------------------------
// Single-block exclusive scan of cnt -> row_off (two-level, 256 threads)
// ---------------------------------------------------------------------------
__global__ __launch_bounds__(256) void scan_kernel(const int* __restrict__ cnt,
                                                   int* __restrict__ row_off) {
  __shared__ int part[256];
  int t = threadIdx.x;
  const int per = (NN + 255) / 256;  // 157
  int beg = t * per;
  int end = beg + per;
  if (end > NN) end = NN;
  int s = 0;
  for (int i = beg; i < end; i++) s += cnt[i];
  part[t] = s;
  __syncthreads();
  for (int off = 1; off < 256; off <<= 1) {
    int add = (t >= off) ? part[t - off] : 0;
    __syncthreads();
    part[t] += add;
    __syncthreads();
  }
  int base = part[t] - s;  // exclusive prefix of this thread's range
  int run = base;
  for (int i = beg; i < end; i++) {
    row_off[i] = run;
    run += cnt[i];
  }
  if (t == 255) row_off[NN] = run;
}

// ---------------------------------------------------------------------------
// CSR fill: csr_src / csr_w (= dis[src]) per incoming edge of each node
// ---------------------------------------------------------------------------
__global__ __launch_bounds__(256) void fill_kernel(
    const int* __restrict__ src, const int* __restrict__ dst,
    const int* __restrict__ row_off, int* __restrict__ cursor,
    const float* __restrict__ dis, int* __restrict__ csr_src,
    float* __restrict__ csr_w, int E) {
  int e = blockIdx.x * 256 + threadIdx.x;
  if (e >= E) return;
  int s = src[e], d = dst[e];
  int p = atomicAdd(&cursor[d], 1);
  int idx = row_off[d] + p;
  csr_src[idx] = s;
  csr_w[idx] = dis[s];
}

// ---------------------------------------------------------------------------
// reg_loss via CSR: mult(j,i) = #occurrences of j among sources of row i.
// reg = sum over edges (i,j) of mult(j,i). Read-only scan, no hash.
// ---------------------------------------------------------------------------
__global__ __launch_bounds__(256) void reg_csr(
    const int* __restrict__ src, const int* __restrict__ dst,
    const int* __restrict__ row_off, const int* __restrict__ csr_src,
    float* __restrict__ out_scalar, int E) {
  int e = blockIdx.x * 256 + threadIdx.x;
  int c = 0;
  if (e < E) {
    int i = src[e], j = dst[e];
    int b = row_off[i], en = row_off[i + 1];
    for (int k = b; k < en; k++) c += (csr_src[k] == j) ? 1 : 0;
  }
  float v = (float)c;
  for (int off = 32; off; off >>= 1) v += __shfl_down(v, off, 64);
  __shared__ float ws[4];
  int lane = threadIdx.x & 63, w = threadIdx.x >> 6;
  if (lane == 0) ws[w] = v;
  __syncthreads();
  if (threadIdx.x == 0) atomicAdd(out_scalar, ws[0] + ws[1] + ws[2] + ws[3]);
}

// ---------------------------------------------------------------------------
// 128-wide normalized aggregation: out[i] = dis[i]*(sum_e dis[src]*H[src] + dis[i]*H[i])
// one wave per node; lane holds 2 columns as float2; edge loop unrolled x4 so
// 4 independent 512B row-gathers are in flight per wave.
// ---------------------------------------------------------------------------
__global__ __launch_bounds__(256) void agg128(
    const float* __restrict__ H, const float* __restrict__ dis,
    const int* __restrict__ row_off, const int* __restrict__ csr_src,
    const float* __restrict__ csr_w, float* __restrict__ out) {
  int node = blockIdx.x * 4 + (threadIdx.x >> 6);
  node = __builtin_amdgcn_readfirstlane(node);
  int lane = threadIdx.x & 63;
  float di = dis[node];
  const float2* hrow = (const float2*)(H + (size_t)node * 128);
  float2 v = hrow[lane];
  float a0 = di * v.x, a1 = di * v.y;
  int beg = row_off[node], end = row_off[node + 1];
  int e = beg;
  for (; e + 4 <= end; e += 4) {
    int s0 = csr_src[e + 0], s1 = csr_src[e + 1];
    int s2 = csr_src[e + 2], s3 = csr_src[e + 3];
    float w0 = csr_w[e + 0], w1 = csr_w[e + 1];
    float w2 = csr_w[e + 2], w3 = csr_w[e + 3];
    float2 u0 = ((const float2*)(H + (size_t)s0 * 128))[lane];
    float2 u1 = ((const float2*)(H + (size_t)s1 * 128))[lane];
    float2 u2 = ((const float2*)(H + (size_t)s2 * 128))[lane];
    float2 u3 = ((const float2*)(H + (size_t)s3 * 128))[lane];
    a0 += w0 * u0.x; a1 += w0 * u0.y;
    a0 += w1 * u1.x; a1 += w1 * u1.y;
    a0 += w2 * u2.x; a1 += w2 * u2.y;
    a0 += w3 * u3.x; a1 += w3 * u3.y;
  }
  for (; e < end; e++) {
    int s = csr_src[e];
    float w = csr_w[e];
    float2 u = ((const float2*)(H + (size_t)s * 128))[lane];
    a0 += w * u.x;
    a1 += w * u.y;
  }
  float2 o;
  o.x = di * a0;
  o.y = di * a1;
  ((float2*)(out + (size_t)node * 128))[lane] = o;
}

// ---------------------------------------------------------------------------
// fp32 GEMM: out[M x 128] = A[M x 128] @ W[128 x 128] + b (opt relu)
// 64-row tiles, K-tiles of 64; XT (transposed) + W tile in LDS; 8x4 per thread
// ---------------------------------------------------------------------------
__global__ __launch_bounds__(256) void gemm128(
    const float* __restrict__ A, const float* __restrict__ W,
    const float* __restrict__ bias, float* __restrict__ out, int relu) {
  __shared__ float XT[64][68];    // [k][row]
  __shared__ float Ws[64][128];   // [k][col]
  int t = threadIdx.x;
  int tx = t & 31, ty = t >> 5;
  int rowBase = blockIdx.x * 64;
  float acc[8][4] = {};
  for (int kt = 0; kt < 128; kt += 64) {
    {
      int kk = (t & 15) * 4;
      int r0 = t >> 4;
      for (int i = 0; i < 4; i++) {
        int r = r0 + i * 16;
        float4 v = *(const float4*)&A[(size_t)(rowBase + r) * 128 + kt + kk];
        XT[kk + 0][r] = v.x;
        XT[kk + 1][r] = v.y;
        XT[kk + 2][r] = v.z;
        XT[kk + 3][r] = v.w;
      }
    }
    {
      int c4 = (t & 31) * 4;
      int kr = t >> 5;
      for (int i = 0; i < 8; i++) {
        int k = kr + i * 8;
        *(float4*)&Ws[k][c4] = *(const float4*)&W[(size_t)(kt + k) * 128 + c4];
      }
    }
    __syncthreads();
#pragma unroll 8
    for (int k = 0; k < 64; k++) {
      float a[8];
      *(float4*)&a[0] = *(const float4*)&XT[k][ty * 8];
      *(float4*)&a[4] = *(const float4*)&XT[k][ty * 8 + 4];
      float4 b = *(const float4*)&Ws[k][tx * 4];
#pragma unroll
      for (int i = 0; i < 8; i++) {
        acc[i][0] += a[i] * b.x;
        acc[i][1] += a[i] * b.y;
        acc[i][2] += a[i] * b.z;
        acc[i][3] += a[i] * b.w;
      }
    }
    __syncthreads();
  }
  float4 bv = *(const float4*)&bias[tx * 4];
  for (int i = 0; i < 8; i++) {
    int r = rowBase + ty * 8 + i;
    float4 o;
    o.x = acc[i][0] + bv.x;
    o.y = acc[i][1] + bv.y;
    o.z = acc[i][2] + bv.z;
    o.w = acc[i][3] + bv.w;
    if (relu) {
      o.x = fmaxf(o.x, 0.f);
      o.y = fmaxf(o.y, 0.f);
      o.z = fmaxf(o.z, 0.f);
      o.w = fmaxf(o.w, 0.f);
    }
    *(float4*)&out[(size_t)r * 128 + tx * 4] = o;
  }
}

// ---------------------------------------------------------------------------
// GEMM 128 -> 40 (no bias): one wave per row, W3 in LDS
// ---------------------------------------------------------------------------
__global__ __launch_bounds__(256) void gemm40(const float* __restrict__ A,
                                              const float* __restrict__ W3,
                                              float* __restrict__ G) {
  __shared__ float Ws[128 * 40];
  int t = threadIdx.x;
  for (int i = t; i < 128 * 40; i += 256) Ws[i] = W3[i];
  __syncthreads();
  int node = __builtin_amdgcn_readfirstlane(blockIdx.x * 4 + (t >> 6));
  int lane = t & 63;
  int cl = lane < 40 ? lane : 39;
  const float* arow = A + (size_t)node * 128;
  float acc = 0.f;
#pragma unroll 8
  for (int k = 0; k < 128; k++) acc += arow[k] * Ws[k * 40 + cl];
  if (lane < 40) G[(size_t)node * 40 + lane] = acc;
}

// ---------------------------------------------------------------------------
// fused: 40-wide aggregation + bias + log_softmax -> d_out (edge loop x4)
// ---------------------------------------------------------------------------
__global__ __launch_bounds__(256) void agg40_softmax(
    const float* __restrict__ G, const float* __restrict__ dis,
    const int* __restrict__ row_off, const int* __restrict__ csr_src,
    const float* __restrict__ csr_w, const float* __restrict__ b3,
    float* __restrict__ outp) {
  int node = __builtin_amdgcn_readfirstlane(blockIdx.x * 4 + (threadIdx.x >> 6));
  int lane = threadIdx.x & 63;
  int cl = lane < 40 ? lane : 39;
  float di = dis[node];
  float a = di * G[(size_t)node * 40 + cl];
  int beg = row_off[node], end = row_off[node + 1];
  int e = beg;
  for (; e + 4 <= end; e += 4) {
    int s0 = csr_src[e + 0], s1 = csr_src[e + 1];
    int s2 = csr_src[e + 2], s3 = csr_src[e + 3];
    float w0 = csr_w[e + 0], w1 = csr_w[e + 1];
    float w2 = csr_w[e + 2], w3 = csr_w[e + 3];
    float g0 = G[(size_t)s0 * 40 + cl];
    float g1 = G[(size_t)s1 * 40 + cl];
    float g2 = G[(size_t)s2 * 40 + cl];
    float g3 = G[(size_t)s3 * 40 + cl];
    a += w0 * g0 + w1 * g1 + w2 * g2 + w3 * g3;
  }
  for (; e < end; e++) {
    a += csr_w[e] * G[(size_t)csr_src[e] * 40 + cl];
  }
  float o = di * a + b3[cl];
  float m = (lane < 40) ? o : -1e30f;
  for (int off = 32; off; off >>= 1) m = fmaxf(m, __shfl_xor(m, off, 64));
  float ex = (lane < 40) ? expf(o - m) : 0.f;
  float ssum = ex;
  for (int off = 32; off; off >>= 1) ssum += __shfl_xor(ssum, off, 64);
  float res = o - m - logf(ssum);
  if (lane < 40) outp[(size_t)node * 40 + lane] = res;
}

// ---------------------------------------------------------------------------
extern "C" void kernel_launch(void* const* d_in, const int* in_sizes, int n_in,
                              void* d_out, int out_size, void* d_ws,
                              size_t ws_size, hipStream_t stream) {
  const float* X = (const float*)d_in[0];
  const int* ei = (const int*)d_in[1];
  const float* W1 = (const float*)d_in[2];
  const float* b1 = (const float*)d_in[3];
  const float* W2 = (const float*)d_in[4];
  const float* b2 = (const float*)d_in[5];
  const float* W3 = (const float*)d_in[6];
  const float* b3 = (const float*)d_in[7];
  float* out = (float*)d_out;

  const int E = EE;
  const int* src = ei;
  const int* dst = ei + E;

  // workspace carve-up (256B aligned)
  char* w = (char*)d_ws;
  auto carve = [&](size_t bytes) {
    char* p = w;
    w += (bytes + 255) & ~(size_t)255;
    return p;
  };
  int* cnt = (int*)carve(NN * 4);
  float* dis = (float*)carve(NN * 4);
  int* row_off = (int*)carve((NN + 1) * 4);
  int* cursor = (int*)carve(NN * 4);
  int* csr_src = (int*)carve((size_t)EE * 4);
  float* csr_w = (float*)carve((size_t)EE * 4);
  float* B_agg = (float*)carve((size_t)NN * 128 * 4);
  float* B_h = (float*)carve((size_t)NN * 128 * 4);
  float* G3 = B_agg;  // reuse: B_agg is dead by the time G3 is produced

  hipMemsetAsync(cnt, 0, NN * 4, stream);
  hipMemsetAsync(cursor, 0, NN * 4, stream);
  hipMemsetAsync((char*)d_out + (size_t)NN * 40 * 4, 0, 4, stream);

  const int EB = (EE + 255) / 256;   // 2500
  const int NB = (NN + 255) / 256;   // 157
  const int WB = NN / 4;             // 10000 (wave-per-node kernels)

  edge_pass1<<<EB, 256, 0, stream>>>(dst, cnt, E);
  dis_kernel<<<NB, 256, 0, stream>>>(cnt, dis);
  scan_kernel<<<1, 256, 0, stream>>>(cnt, row_off);
  fill_kernel<<<EB, 256, 0, stream>>>(src, dst, row_off, cursor, dis, csr_src,
                                      csr_w, E);
  reg_csr<<<EB, 256, 0, stream>>>(src, dst, row_off, csr_src,
                                  out + (size_t)NN * 40, E);

  // layer 1: agg(X) -> B_agg ; gemm+relu -> B_h
  agg128<<<WB, 256, 0, stream>>>(X, dis, row_off, csr_src, csr_w, B_agg);
  gemm128<<<NN / 64, 256, 0, stream>>>(B_agg, W1, b1, B_h, 1);
  // layer 2: agg(B_h) -> B_agg ; gemm+relu -> B_h
  agg128<<<WB, 256, 0, stream>>>(B_h, dis, row_off, csr_src, csr_w, B_agg);
  gemm128<<<NN / 64, 256, 0, stream>>>(B_agg, W2, b2, B_h, 1);
  // layer 3: gemm40(B_h) -> G3 ; fused agg + bias + log_softmax -> out
  gemm40<<<WB, 256, 0, stream>>>(B_h, W3, G3);
  agg40_softmax<<<WB, 256, 0, stream>>>(G3, dis, row_off, csr_src, csr_w, b3,
                                        out);
}

// Round 3
// 466.165 us; speedup vs baseline: 1.2098x; 1.0206x over previous
//
#include <hip/hip_runtime.h>
#include <hip/hip_bf16.h>
#include <math.h>

#define NN 40000
#define EE 640000

// ---- bf16 helpers ---------------------------------------------------------
__device__ __forceinline__ unsigned bf16rne(float x) {
  unsigned u = __float_as_uint(x);
  return (u + 0x7fffu + ((u >> 16) & 1u)) >> 16;
}
__device__ __forceinline__ unsigned packbf2(float lo, float hi) {
  return bf16rne(lo) | (bf16rne(hi) << 16);
}
// unpack uint -> two floats (elem0 = low 16 bits)
__device__ __forceinline__ float bflo(unsigned u) {
  return __uint_as_float(u << 16);
}
__device__ __forceinline__ float bfhi(unsigned u) {
  return __uint_as_float(u & 0xffff0000u);
}

// ---------------------------------------------------------------------------
// in-degree counts; 4 edges per thread (int4), one atomic per edge
// ---------------------------------------------------------------------------
__global__ __launch_bounds__(256) void edge_pass1(
    const int4* __restrict__ dst4, int* __restrict__ cnt) {
  int e = blockIdx.x * 256 + threadIdx.x;  // e indexes groups of 4
  if (e >= EE / 4) return;
  int4 d = dst4[e];
  atomicAdd(&cnt[d.x], 1);
  atomicAdd(&cnt[d.y], 1);
  atomicAdd(&cnt[d.z], 1);
  atomicAdd(&cnt[d.w], 1);
}

// ---------------------------------------------------------------------------
// single-block scan: row_off (exclusive), cursor (=row_off), dis = rsqrt(c+1)
// 1024 threads x 40 elements, shuffle block-scan. Replaces the 65us
// 256-thread serial version.
// ---------------------------------------------------------------------------
__global__ __launch_bounds__(1024) void scan_kernel(
    const int* __restrict__ cnt, int* __restrict__ row_off,
    int* __restrict__ cursor, float* __restrict__ dis) {
  int t = threadIdx.x;
  const int PER = 40;  // 1024*40 = 40960 >= 40000
  int beg = t * PER;
  int end = beg + PER;
  if (end > NN) end = NN;
  int s = 0;
  if (beg < NN && end == beg + PER) {
    const int4* p = (const int4*)(cnt + beg);
#pragma unroll
    for (int i = 0; i < 10; i++) {
      int4 v = p[i];
      s += v.x + v.y + v.z + v.w;
    }
  } else {
    for (int i = beg; i < end; i++) s += cnt[i];
  }
  // wave-64 inclusive scan
  int lane = t & 63, w = t >> 6;
  int v = s;
#pragma unroll
  for (int off = 1; off < 64; off <<= 1) {
    int u = __shfl_up(v, off, 64);
    if (lane >= off) v += u;
  }
  __shared__ int wsum[16];
  if (lane == 63) wsum[w] = v;
  __syncthreads();
  if (t < 16) {
    int x = wsum[t];
#pragma unroll
    for (int off = 1; off < 16; off <<= 1) {
      int u = __shfl_up(x, off, 64);
      if (t >= off) x += u;
    }
    wsum[t] = x;
  }
  __syncthreads();
  int base = v - s + (w ? wsum[w - 1] : 0);  // exclusive prefix
  int run = base;
  for (int i = beg; i < end; i++) {
    int c = cnt[i];
    row_off[i] = run;
    cursor[i] = run;
    dis[i] = rsqrtf((float)(c + 1));
    run += c;
  }
  if (t == 1023) row_off[NN] = run;
}

// ---------------------------------------------------------------------------
// CSR fill: cursor pre-seeded with row_off, so atomicAdd returns final index
// ---------------------------------------------------------------------------
__global__ __launch_bounds__(256) void fill_kernel(
    const int4* __restrict__ src4, const int4* __restrict__ dst4,
    int* __restrict__ cursor, const float* __restrict__ dis,
    int* __restrict__ csr_src, float* __restrict__ csr_w) {
  int e = blockIdx.x * 256 + threadIdx.x;
  if (e >= EE / 4) return;
  int4 s = src4[e];
  int4 d = dst4[e];
  int i0 = atomicAdd(&cursor[d.x], 1);
  int i1 = atomicAdd(&cursor[d.y], 1);
  int i2 = atomicAdd(&cursor[d.z], 1);
  int i3 = atomicAdd(&cursor[d.w], 1);
  csr_src[i0] = s.x; csr_w[i0] = dis[s.x];
  csr_src[i1] = s.y; csr_w[i1] = dis[s.y];
  csr_src[i2] = s.z; csr_w[i2] = dis[s.z];
  csr_src[i3] = s.w; csr_w[i3] = dis[s.w];
}

// ---------------------------------------------------------------------------
// reg_loss via CSR row scan (read-only; no hash)
// ---------------------------------------------------------------------------
__global__ __launch_bounds__(256) void reg_csr(
    const int* __restrict__ src, const int* __restrict__ dst,
    const int* __restrict__ row_off, const int* __restrict__ csr_src,
    float* __restrict__ out_scalar, int E) {
  int e = blockIdx.x * 256 + threadIdx.x;
  int c = 0;
  if (e < E) {
    int i = src[e], j = dst[e];
    int b = row_off[i], en = row_off[i + 1];
    for (int k = b; k < en; k++) c += (csr_src[k] == j) ? 1 : 0;
  }
  float v = (float)c;
  for (int off = 32; off; off >>= 1) v += __shfl_down(v, off, 64);
  __shared__ float ws[4];
  int lane = threadIdx.x & 63, w = threadIdx.x >> 6;
  if (lane == 0) ws[w] = v;
  __syncthreads();
  if (threadIdx.x == 0) atomicAdd(out_scalar, ws[0] + ws[1] + ws[2] + ws[3]);
}

// ---------------------------------------------------------------------------
// fp32 X -> bf16 table (row-major 128 wide); 8 elems per thread
// ---------------------------------------------------------------------------
__global__ __launch_bounds__(256) void cvt_bf16(const float4* __restrict__ in,
                                                uint2* __restrict__ outp,
                                                int n8) {
  int i = blockIdx.x * 256 + threadIdx.x;
  if (i >= n8) return;
  float4 a = in[i * 2], b = in[i * 2 + 1];
  uint2 o;
  o.x = packbf2(a.x, a.y) ;
  o.x = packbf2(a.x, a.y);
  o.y = packbf2(a.z, a.w);
  outp[i * 2] = o;
  uint2 p;
  p.x = packbf2(b.x, b.y);
  p.y = packbf2(b.z, b.w);
  outp[i * 2 + 1] = p;
}

// ---------------------------------------------------------------------------
// 128-wide aggregation over bf16 table: out fp32
// one wave per node; lane holds 2 columns (one uint); edge loop x4
// ---------------------------------------------------------------------------
__global__ __launch_bounds__(256) void agg128b(
    const unsigned* __restrict__ Hb, const float* __restrict__ dis,
    const int* __restrict__ row_off, const int* __restrict__ csr_src,
    const float* __restrict__ csr_w, float* __restrict__ out) {
  int node = __builtin_amdgcn_readfirstlane(blockIdx.x * 4 + (threadIdx.x >> 6));
  int lane = threadIdx.x & 63;
  float di = dis[node];
  unsigned v = Hb[(size_t)node * 64 + lane];
  float a0 = di * bflo(v), a1 = di * bfhi(v);
  int beg = row_off[node], end = row_off[node + 1];
  int e = beg;
  for (; e + 4 <= end; e += 4) {
    int s0 = csr_src[e + 0], s1 = csr_src[e + 1];
    int s2 = csr_src[e + 2], s3 = csr_src[e + 3];
    float w0 = csr_w[e + 0], w1 = csr_w[e + 1];
    float w2 = csr_w[e + 2], w3 = csr_w[e + 3];
    unsigned u0 = Hb[(size_t)s0 * 64 + lane];
    unsigned u1 = Hb[(size_t)s1 * 64 + lane];
    unsigned u2 = Hb[(size_t)s2 * 64 + lane];
    unsigned u3 = Hb[(size_t)s3 * 64 + lane];
    a0 += w0 * bflo(u0); a1 += w0 * bfhi(u0);
    a0 += w1 * bflo(u1); a1 += w1 * bfhi(u1);
    a0 += w2 * bflo(u2); a1 += w2 * bfhi(u2);
    a0 += w3 * bflo(u3); a1 += w3 * bfhi(u3);
  }
  for (; e < end; e++) {
    unsigned u = Hb[(size_t)csr_src[e] * 64 + lane];
    float w = csr_w[e];
    a0 += w * bflo(u);
    a1 += w * bfhi(u);
  }
  float2 o;
  o.x = di * a0;
  o.y = di * a1;
  ((float2*)(out + (size_t)node * 128))[lane] = o;
}

// ---------------------------------------------------------------------------
// fp32 GEMM: out[M x 128] = A[M x 128] @ W[128 x 128] + b, relu.
// outMode: 0 -> fp32 out ; 1 -> bf16-packed out (for next agg gather table)
// ---------------------------------------------------------------------------
__global__ __launch_bounds__(256) void gemm128(
    const float* __restrict__ A, const float* __restrict__ W,
    const float* __restrict__ bias, float* __restrict__ outF,
    unsigned* __restrict__ outB, int outMode) {
  __shared__ float XT[64][68];    // [k][row]
  __shared__ float Ws[64][128];   // [k][col]
  int t = threadIdx.x;
  int tx = t & 31, ty = t >> 5;
  int rowBase = blockIdx.x * 64;
  float acc[8][4] = {};
  for (int kt = 0; kt < 128; kt += 64) {
    {
      int kk = (t & 15) * 4;
      int r0 = t >> 4;
      for (int i = 0; i < 4; i++) {
        int r = r0 + i * 16;
        float4 v = *(const float4*)&A[(size_t)(rowBase + r) * 128 + kt + kk];
        XT[kk + 0][r] = v.x;
        XT[kk + 1][r] = v.y;
        XT[kk + 2][r] = v.z;
        XT[kk + 3][r] = v.w;
      }
    }
    {
      int c4 = (t & 31) * 4;
      int kr = t >> 5;
      for (int i = 0; i < 8; i++) {
        int k = kr + i * 8;
        *(float4*)&Ws[k][c4] = *(const float4*)&W[(size_t)(kt + k) * 128 + c4];
      }
    }
    __syncthreads();
#pragma unroll 8
    for (int k = 0; k < 64; k++) {
      float a[8];
      *(float4*)&a[0] = *(const float4*)&XT[k][ty * 8];
      *(float4*)&a[4] = *(const float4*)&XT[k][ty * 8 + 4];
      float4 b = *(const float4*)&Ws[k][tx * 4];
#pragma unroll
      for (int i = 0; i < 8; i++) {
        acc[i][0] += a[i] * b.x;
        acc[i][1] += a[i] * b.y;
        acc[i][2] += a[i] * b.z;
        acc[i][3] += a[i] * b.w;
      }
    }
    __syncthreads();
  }
  float4 bv = *(const float4*)&bias[tx * 4];
  for (int i = 0; i < 8; i++) {
    int r = rowBase + ty * 8 + i;
    float x0 = fmaxf(acc[i][0] + bv.x, 0.f);
    float x1 = fmaxf(acc[i][1] + bv.y, 0.f);
    float x2 = fmaxf(acc[i][2] + bv.z, 0.f);
    float x3 = fmaxf(acc[i][3] + bv.w, 0.f);
    if (outMode == 0) {
      float4 o = {x0, x1, x2, x3};
      *(float4*)&outF[(size_t)r * 128 + tx * 4] = o;
    } else {
      uint2 o;
      o.x = packbf2(x0, x1);
      o.y = packbf2(x2, x3);
      *(uint2*)&outB[(size_t)r * 64 + tx * 2] = o;
    }
  }
}

// ---------------------------------------------------------------------------
// GEMM 128 -> 40 (no bias): one wave per row, W3 in LDS
// ---------------------------------------------------------------------------
__global__ __launch_bounds__(256) void gemm40(const float* __restrict__ A,
                                              const float* __restrict__ W3,
                                              float* __restrict__ G) {
  __shared__ float Ws[128 * 40];
  int t = threadIdx.x;
  for (int i = t; i < 128 * 40; i += 256) Ws[i] = W3[i];
  __syncthreads();
  int node = __builtin_amdgcn_readfirstlane(blockIdx.x * 4 + (t >> 6));
  int lane = t & 63;
  int cl = lane < 40 ? lane : 39;
  const float* arow = A + (size_t)node * 128;
  float acc = 0.f;
#pragma unroll 8
  for (int k = 0; k < 128; k++) acc += arow[k] * Ws[k * 40 + cl];
  if (lane < 40) G[(size_t)node * 40 + lane] = acc;
}

// ---------------------------------------------------------------------------
// fused: 40-wide aggregation + bias + log_softmax -> d_out (edge loop x4)
// ---------------------------------------------------------------------------
__global__ __launch_bounds__(256) void agg40_softmax(
    const float* __restrict__ G, const float* __restrict__ dis,
    const int* __restrict__ row_off, const int* __restrict__ csr_src,
    const float* __restrict__ csr_w, const float* __restrict__ b3,
    float* __restrict__ outp) {
  int node = __builtin_amdgcn_readfirstlane(blockIdx.x * 4 + (threadIdx.x >> 6));
  int lane = threadIdx.x & 63;
  int cl = lane < 40 ? lane : 39;
  float di = dis[node];
  float a = di * G[(size_t)node * 40 + cl];
  int beg = row_off[node], end = row_off[node + 1];
  int e = beg;
  for (; e + 4 <= end; e += 4) {
    int s0 = csr_src[e + 0], s1 = csr_src[e + 1];
    int s2 = csr_src[e + 2], s3 = csr_src[e + 3];
    float w0 = csr_w[e + 0], w1 = csr_w[e + 1];
    float w2 = csr_w[e + 2], w3 = csr_w[e + 3];
    float g0 = G[(size_t)s0 * 40 + cl];
    float g1 = G[(size_t)s1 * 40 + cl];
    float g2 = G[(size_t)s2 * 40 + cl];
    float g3 = G[(size_t)s3 * 40 + cl];
    a += w0 * g0 + w1 * g1 + w2 * g2 + w3 * g3;
  }
  for (; e < end; e++) {
    a += csr_w[e] * G[(size_t)csr_src[e] * 40 + cl];
  }
  float o = di * a + b3[cl];
  float m = (lane < 40) ? o : -1e30f;
  for (int off = 32; off; off >>= 1) m = fmaxf(m, __shfl_xor(m, off, 64));
  float ex = (lane < 40) ? expf(o - m) : 0.f;
  float ssum = ex;
  for (int off = 32; off; off >>= 1) ssum += __shfl_xor(ssum, off, 64);
  float res = o - m - logf(ssum);
  if (lane < 40) outp[(size_t)node * 40 + lane] = res;
}

// ---------------------------------------------------------------------------
extern "C" void kernel_launch(void* const* d_in, const int* in_sizes, int n_in,
                              void* d_out, int out_size, void* d_ws,
                              size_t ws_size, hipStream_t stream) {
  const float* X = (const float*)d_in[0];
  const int* ei = (const int*)d_in[1];
  const float* W1 = (const float*)d_in[2];
  const float* b1 = (const float*)d_in[3];
  const float* W2 = (const float*)d_in[4];
  const float* b2 = (const float*)d_in[5];
  const float* W3 = (const float*)d_in[6];
  const float* b3 = (const float*)d_in[7];
  float* out = (float*)d_out;

  const int E = EE;
  const int* src = ei;
  const int* dst = ei + E;

  // workspace carve-up (256B aligned)
  char* w = (char*)d_ws;
  auto carve = [&](size_t bytes) {
    char* p = w;
    w += (bytes + 255) & ~(size_t)255;
    return p;
  };
  int* cnt = (int*)carve(NN * 4);
  float* dis = (float*)carve(NN * 4);
  int* row_off = (int*)carve((NN + 1) * 4);
  int* cursor = (int*)carve(NN * 4);
  int* csr_src = (int*)carve((size_t)EE * 4);
  float* csr_w = (float*)carve((size_t)EE * 4);
  float* B_agg = (float*)carve((size_t)NN * 128 * 4);       // 20.5 MB
  char* blk = carve((size_t)NN * 128 * 4);                  // 20.5 MB shared
  unsigned* Xb = (unsigned*)blk;                            // bf16 X (10.25MB)
  unsigned* H1b = (unsigned*)(blk + (size_t)NN * 128 * 2);  // bf16 h1 (10.25MB)
  float* h2 = (float*)blk;   // layer-2 out, alias (Xb,H1b dead by then)
  float* G3 = B_agg;         // layer-3 pre-agg, alias (B_agg dead by then)

  hipMemsetAsync(cnt, 0, NN * 4, stream);
  hipMemsetAsync((char*)d_out + (size_t)NN * 40 * 4, 0, 4, stream);

  const int E4B = (EE / 4 + 255) / 256;  // 625
  const int EB = (EE + 255) / 256;       // 2500
  const int WB = NN / 4;                 // 10000

  edge_pass1<<<E4B, 256, 0, stream>>>((const int4*)dst, cnt);
  scan_kernel<<<1, 1024, 0, stream>>>(cnt, row_off, cursor, dis);
  fill_kernel<<<E4B, 256, 0, stream>>>((const int4*)src, (const int4*)dst,
                                       cursor, dis, csr_src, csr_w);
  reg_csr<<<EB, 256, 0, stream>>>(src, dst, row_off, csr_src,
                                  out + (size_t)NN * 40, E);

  // X -> bf16 table
  cvt_bf16<<<(NN * 128 / 8 + 255) / 256, 256, 0, stream>>>(
      (const float4*)X, (uint2*)Xb, NN * 128 / 8);
  // layer 1: agg(Xb) -> B_agg ; gemm+relu -> H1b (bf16)
  agg128b<<<WB, 256, 0, stream>>>(Xb, dis, row_off, csr_src, csr_w, B_agg);
  gemm128<<<NN / 64, 256, 0, stream>>>(B_agg, W1, b1, nullptr, H1b, 1);
  // layer 2: agg(H1b) -> B_agg ; gemm+relu -> h2 (fp32)
  agg128b<<<WB, 256, 0, stream>>>(H1b, dis, row_off, csr_src, csr_w, B_agg);
  gemm128<<<NN / 64, 256, 0, stream>>>(B_agg, W2, b2, h2, nullptr, 0);
  // layer 3: gemm40(h2) -> G3 ; fused agg + bias + log_softmax -> out
  gemm40<<<WB, 256, 0, stream>>>(h2, W3, G3);
  agg40_softmax<<<WB, 256, 0, stream>>>(G3, dis, row_off, csr_src, csr_w, b3,
                                        out);
}

// Round 4
// 378.457 us; speedup vs baseline: 1.4902x; 1.2318x over previous
//
#include <hip/hip_runtime.h>
#include <hip/hip_bf16.h>
#include <math.h>

#define NN 40000
#define EE 640000

// ---- bf16 helpers ---------------------------------------------------------
__device__ __forceinline__ unsigned bf16rne(float x) {
  unsigned u = __float_as_uint(x);
  return (u + 0x7fffu + ((u >> 16) & 1u)) >> 16;
}
__device__ __forceinline__ unsigned packbf2(float lo, float hi) {
  return bf16rne(lo) | (bf16rne(hi) << 16);
}
__device__ __forceinline__ float bflo(unsigned u) {
  return __uint_as_float(u << 16);
}
__device__ __forceinline__ float bfhi(unsigned u) {
  return __uint_as_float(u & 0xffff0000u);
}

// ---------------------------------------------------------------------------
// in-degree counts; 4 edges per thread (int4), one atomic per edge
// ---------------------------------------------------------------------------
__global__ __launch_bounds__(256) void edge_pass1(
    const int4* __restrict__ dst4, int* __restrict__ cnt) {
  int e = blockIdx.x * 256 + threadIdx.x;
  if (e >= EE / 4) return;
  int4 d = dst4[e];
  atomicAdd(&cnt[d.x], 1);
  atomicAdd(&cnt[d.y], 1);
  atomicAdd(&cnt[d.z], 1);
  atomicAdd(&cnt[d.w], 1);
}

// ---------------------------------------------------------------------------
// single-block chunked scan, fully COALESCED.
// R3 post-mortem: per-thread serial ranges made every wave-store hit 64
// cache lines (160B lane stride) -> 103us on one CU. Now lane t of chunk c
// handles elements c*4096 + 4t: every load/store is one coalesced 1KB/wave
// transaction. 10 chunks of 4096 cover NN=40000.
// ---------------------------------------------------------------------------
__global__ __launch_bounds__(1024) void scan_kernel(
    const int4* __restrict__ cnt4, int* __restrict__ row_off,
    int* __restrict__ cursor, float* __restrict__ dis) {
  __shared__ int wsum[16];
  __shared__ int btot;
  int t = threadIdx.x;
  int lane = t & 63, w = t >> 6;
  int running = 0;
  for (int c = 0; c < 10; c++) {
    int idx4 = c * 1024 + t;  // int4 index; element = idx4*4
    bool ok = idx4 * 4 < NN;
    int4 v = ok ? cnt4[idx4] : int4{0, 0, 0, 0};
    int ts = v.x + v.y + v.z + v.w;
    int incl = ts;
#pragma unroll
    for (int off = 1; off < 64; off <<= 1) {
      int u = __shfl_up(incl, off, 64);
      if (lane >= off) incl += u;
    }
    if (lane == 63) wsum[w] = incl;
    __syncthreads();
    if (t < 16) {
      int x = wsum[t];
#pragma unroll
      for (int off = 1; off < 16; off <<= 1) {
        int u = __shfl_up(x, off, 64);
        if (t >= off) x += u;
      }
      wsum[t] = x;
      if (t == 15) btot = x;
    }
    __syncthreads();
    int base = running + (w ? wsum[w - 1] : 0) + (incl - ts);
    if (ok) {
      int4 r;
      r.x = base;
      r.y = base + v.x;
      r.z = r.y + v.y;
      r.w = r.z + v.z;
      ((int4*)row_off)[idx4] = r;
      ((int4*)cursor)[idx4] = r;
      float4 d;
      d.x = rsqrtf((float)(v.x + 1));
      d.y = rsqrtf((float)(v.y + 1));
      d.z = rsqrtf((float)(v.z + 1));
      d.w = rsqrtf((float)(v.w + 1));
      ((float4*)dis)[idx4] = d;
    }
    running += btot;
    __syncthreads();  // protect wsum/btot before next chunk overwrites
  }
  if (t == 0) row_off[NN] = running;
}

// ---------------------------------------------------------------------------
// CSR fill: cursor pre-seeded with row_off, so atomicAdd returns final index
// ---------------------------------------------------------------------------
__global__ __launch_bounds__(256) void fill_kernel(
    const int4* __restrict__ src4, const int4* __restrict__ dst4,
    int* __restrict__ cursor, const float* __restrict__ dis,
    int* __restrict__ csr_src, float* __restrict__ csr_w) {
  int e = blockIdx.x * 256 + threadIdx.x;
  if (e >= EE / 4) return;
  int4 s = src4[e];
  int4 d = dst4[e];
  int i0 = atomicAdd(&cursor[d.x], 1);
  int i1 = atomicAdd(&cursor[d.y], 1);
  int i2 = atomicAdd(&cursor[d.z], 1);
  int i3 = atomicAdd(&cursor[d.w], 1);
  csr_src[i0] = s.x; csr_w[i0] = dis[s.x];
  csr_src[i1] = s.y; csr_w[i1] = dis[s.y];
  csr_src[i2] = s.z; csr_w[i2] = dis[s.z];
  csr_src[i3] = s.w; csr_w[i3] = dis[s.w];
}

// ---------------------------------------------------------------------------
// reg_loss via CSR row scan (read-only; no hash)
// ---------------------------------------------------------------------------
__global__ __launch_bounds__(256) void reg_csr(
    const int* __restrict__ src, const int* __restrict__ dst,
    const int* __restrict__ row_off, const int* __restrict__ csr_src,
    float* __restrict__ out_scalar, int E) {
  int e = blockIdx.x * 256 + threadIdx.x;
  int c = 0;
  if (e < E) {
    int i = src[e], j = dst[e];
    int b = row_off[i], en = row_off[i + 1];
    for (int k = b; k < en; k++) c += (csr_src[k] == j) ? 1 : 0;
  }
  float v = (float)c;
  for (int off = 32; off; off >>= 1) v += __shfl_down(v, off, 64);
  __shared__ float ws[4];
  int lane = threadIdx.x & 63, w = threadIdx.x >> 6;
  if (lane == 0) ws[w] = v;
  __syncthreads();
  if (threadIdx.x == 0) atomicAdd(out_scalar, ws[0] + ws[1] + ws[2] + ws[3]);
}

// ---------------------------------------------------------------------------
// fp32 X -> bf16 table (row-major 128 wide); 8 elems per thread
// ---------------------------------------------------------------------------
__global__ __launch_bounds__(256) void cvt_bf16(const float4* __restrict__ in,
                                                uint2* __restrict__ outp,
                                                int n8) {
  int i = blockIdx.x * 256 + threadIdx.x;
  if (i >= n8) return;
  float4 a = in[i * 2], b = in[i * 2 + 1];
  uint2 o;
  o.x = packbf2(a.x, a.y);
  o.y = packbf2(a.z, a.w);
  outp[i * 2] = o;
  uint2 p;
  p.x = packbf2(b.x, b.y);
  p.y = packbf2(b.z, b.w);
  outp[i * 2 + 1] = p;
}

// ---------------------------------------------------------------------------
// 128-wide aggregation over bf16 table: out fp32
// one wave per node; lane holds 2 columns (one uint); edge loop x4
// ---------------------------------------------------------------------------
__global__ __launch_bounds__(256) void agg128b(
    const unsigned* __restrict__ Hb, const float* __restrict__ dis,
    const int* __restrict__ row_off, const int* __restrict__ csr_src,
    const float* __restrict__ csr_w, float* __restrict__ out) {
  int node = __builtin_amdgcn_readfirstlane(blockIdx.x * 4 + (threadIdx.x >> 6));
  int lane = threadIdx.x & 63;
  float di = dis[node];
  unsigned v = Hb[(size_t)node * 64 + lane];
  float a0 = di * bflo(v), a1 = di * bfhi(v);
  int beg = row_off[node], end = row_off[node + 1];
  int e = beg;
  for (; e + 4 <= end; e += 4) {
    int s0 = csr_src[e + 0], s1 = csr_src[e + 1];
    int s2 = csr_src[e + 2], s3 = csr_src[e + 3];
    float w0 = csr_w[e + 0], w1 = csr_w[e + 1];
    float w2 = csr_w[e + 2], w3 = csr_w[e + 3];
    unsigned u0 = Hb[(size_t)s0 * 64 + lane];
    unsigned u1 = Hb[(size_t)s1 * 64 + lane];
    unsigned u2 = Hb[(size_t)s2 * 64 + lane];
    unsigned u3 = Hb[(size_t)s3 * 64 + lane];
    a0 += w0 * bflo(u0); a1 += w0 * bfhi(u0);
    a0 += w1 * bflo(u1); a1 += w1 * bfhi(u1);
    a0 += w2 * bflo(u2); a1 += w2 * bfhi(u2);
    a0 += w3 * bflo(u3); a1 += w3 * bfhi(u3);
  }
  for (; e < end; e++) {
    unsigned u = Hb[(size_t)csr_src[e] * 64 + lane];
    float w = csr_w[e];
    a0 += w * bflo(u);
    a1 += w * bfhi(u);
  }
  float2 o;
  o.x = di * a0;
  o.y = di * a1;
  ((float2*)(out + (size_t)node * 128))[lane] = o;
}

// ---------------------------------------------------------------------------
// fp32 GEMM: out[M x 128] = A[M x 128] @ W[128 x 128] + b, relu.
// outMode: 0 -> fp32 out ; 1 -> bf16-packed out (for next agg gather table)
// ---------------------------------------------------------------------------
__global__ __launch_bounds__(256) void gemm128(
    const float* __restrict__ A, const float* __restrict__ W,
    const float* __restrict__ bias, float* __restrict__ outF,
    unsigned* __restrict__ outB, int outMode) {
  __shared__ float XT[64][68];    // [k][row]
  __shared__ float Ws[64][128];   // [k][col]
  int t = threadIdx.x;
  int tx = t & 31, ty = t >> 5;
  int rowBase = blockIdx.x * 64;
  float acc[8][4] = {};
  for (int kt = 0; kt < 128; kt += 64) {
    {
      int kk = (t & 15) * 4;
      int r0 = t >> 4;
      for (int i = 0; i < 4; i++) {
        int r = r0 + i * 16;
        float4 v = *(const float4*)&A[(size_t)(rowBase + r) * 128 + kt + kk];
        XT[kk + 0][r] = v.x;
        XT[kk + 1][r] = v.y;
        XT[kk + 2][r] = v.z;
        XT[kk + 3][r] = v.w;
      }
    }
    {
      int c4 = (t & 31) * 4;
      int kr = t >> 5;
      for (int i = 0; i < 8; i++) {
        int k = kr + i * 8;
        *(float4*)&Ws[k][c4] = *(const float4*)&W[(size_t)(kt + k) * 128 + c4];
      }
    }
    __syncthreads();
#pragma unroll 8
    for (int k = 0; k < 64; k++) {
      float a[8];
      *(float4*)&a[0] = *(const float4*)&XT[k][ty * 8];
      *(float4*)&a[4] = *(const float4*)&XT[k][ty * 8 + 4];
      float4 b = *(const float4*)&Ws[k][tx * 4];
#pragma unroll
      for (int i = 0; i < 8; i++) {
        acc[i][0] += a[i] * b.x;
        acc[i][1] += a[i] * b.y;
        acc[i][2] += a[i] * b.z;
        acc[i][3] += a[i] * b.w;
      }
    }
    __syncthreads();
  }
  float4 bv = *(const float4*)&bias[tx * 4];
  for (int i = 0; i < 8; i++) {
    int r = rowBase + ty * 8 + i;
    float x0 = fmaxf(acc[i][0] + bv.x, 0.f);
    float x1 = fmaxf(acc[i][1] + bv.y, 0.f);
    float x2 = fmaxf(acc[i][2] + bv.z, 0.f);
    float x3 = fmaxf(acc[i][3] + bv.w, 0.f);
    if (outMode == 0) {
      float4 o = {x0, x1, x2, x3};
      *(float4*)&outF[(size_t)r * 128 + tx * 4] = o;
    } else {
      uint2 o;
      o.x = packbf2(x0, x1);
      o.y = packbf2(x2, x3);
      *(uint2*)&outB[(size_t)r * 64 + tx * 2] = o;
    }
  }
}

// ---------------------------------------------------------------------------
// GEMM 128 -> 40 (no bias): one wave per row, W3 in LDS
// ---------------------------------------------------------------------------
__global__ __launch_bounds__(256) void gemm40(const float* __restrict__ A,
                                              const float* __restrict__ W3,
                                              float* __restrict__ G) {
  __shared__ float Ws[128 * 40];
  int t = threadIdx.x;
  for (int i = t; i < 128 * 40; i += 256) Ws[i] = W3[i];
  __syncthreads();
  int node = __builtin_amdgcn_readfirstlane(blockIdx.x * 4 + (t >> 6));
  int lane = t & 63;
  int cl = lane < 40 ? lane : 39;
  const float* arow = A + (size_t)node * 128;
  float acc = 0.f;
#pragma unroll 8
  for (int k = 0; k < 128; k++) acc += arow[k] * Ws[k * 40 + cl];
  if (lane < 40) G[(size_t)node * 40 + lane] = acc;
}

// ---------------------------------------------------------------------------
// fused: 40-wide aggregation + bias + log_softmax -> d_out (edge loop x4)
// ---------------------------------------------------------------------------
__global__ __launch_bounds__(256) void agg40_softmax(
    const float* __restrict__ G, const float* __restrict__ dis,
    const int* __restrict__ row_off, const int* __restrict__ csr_src,
    const float* __restrict__ csr_w, const float* __restrict__ b3,
    float* __restrict__ outp) {
  int node = __builtin_amdgcn_readfirstlane(blockIdx.x * 4 + (threadIdx.x >> 6));
  int lane = threadIdx.x & 63;
  int cl = lane < 40 ? lane : 39;
  float di = dis[node];
  float a = di * G[(size_t)node * 40 + cl];
  int beg = row_off[node], end = row_off[node + 1];
  int e = beg;
  for (; e + 4 <= end; e += 4) {
    int s0 = csr_src[e + 0], s1 = csr_src[e + 1];
    int s2 = csr_src[e + 2], s3 = csr_src[e + 3];
    float w0 = csr_w[e + 0], w1 = csr_w[e + 1];
    float w2 = csr_w[e + 2], w3 = csr_w[e + 3];
    float g0 = G[(size_t)s0 * 40 + cl];
    float g1 = G[(size_t)s1 * 40 + cl];
    float g2 = G[(size_t)s2 * 40 + cl];
    float g3 = G[(size_t)s3 * 40 + cl];
    a += w0 * g0 + w1 * g1 + w2 * g2 + w3 * g3;
  }
  for (; e < end; e++) {
    a += csr_w[e] * G[(size_t)csr_src[e] * 40 + cl];
  }
  float o = di * a + b3[cl];
  float m = (lane < 40) ? o : -1e30f;
  for (int off = 32; off; off >>= 1) m = fmaxf(m, __shfl_xor(m, off, 64));
  float ex = (lane < 40) ? expf(o - m) : 0.f;
  float ssum = ex;
  for (int off = 32; off; off >>= 1) ssum += __shfl_xor(ssum, off, 64);
  float res = o - m - logf(ssum);
  if (lane < 40) outp[(size_t)node * 40 + lane] = res;
}

// ---------------------------------------------------------------------------
extern "C" void kernel_launch(void* const* d_in, const int* in_sizes, int n_in,
                              void* d_out, int out_size, void* d_ws,
                              size_t ws_size, hipStream_t stream) {
  const float* X = (const float*)d_in[0];
  const int* ei = (const int*)d_in[1];
  const float* W1 = (const float*)d_in[2];
  const float* b1 = (const float*)d_in[3];
  const float* W2 = (const float*)d_in[4];
  const float* b2 = (const float*)d_in[5];
  const float* W3 = (const float*)d_in[6];
  const float* b3 = (const float*)d_in[7];
  float* out = (float*)d_out;

  const int E = EE;
  const int* src = ei;
  const int* dst = ei + E;

  // workspace carve-up (256B aligned)
  char* w = (char*)d_ws;
  auto carve = [&](size_t bytes) {
    char* p = w;
    w += (bytes + 255) & ~(size_t)255;
    return p;
  };
  int* cnt = (int*)carve(NN * 4);
  float* dis = (float*)carve(NN * 4);
  int* row_off = (int*)carve((NN + 1) * 4);
  int* cursor = (int*)carve(NN * 4);
  int* csr_src = (int*)carve((size_t)EE * 4);
  float* csr_w = (float*)carve((size_t)EE * 4);
  float* B_agg = (float*)carve((size_t)NN * 128 * 4);       // 20.5 MB
  char* blk = carve((size_t)NN * 128 * 4);                  // 20.5 MB shared
  unsigned* Xb = (unsigned*)blk;                            // bf16 X (10.25MB)
  unsigned* H1b = (unsigned*)(blk + (size_t)NN * 128 * 2);  // bf16 h1 (10.25MB)
  float* h2 = (float*)blk;   // layer-2 out, alias (Xb,H1b dead by then)
  float* G3 = B_agg;         // layer-3 pre-agg, alias (B_agg dead by then)

  hipMemsetAsync(cnt, 0, NN * 4, stream);
  hipMemsetAsync((char*)d_out + (size_t)NN * 40 * 4, 0, 4, stream);

  const int E4B = (EE / 4 + 255) / 256;  // 625
  const int EB = (EE + 255) / 256;       // 2500
  const int WB = NN / 4;                 // 10000

  edge_pass1<<<E4B, 256, 0, stream>>>((const int4*)dst, cnt);
  scan_kernel<<<1, 1024, 0, stream>>>((const int4*)cnt, row_off, cursor, dis);
  fill_kernel<<<E4B, 256, 0, stream>>>((const int4*)src, (const int4*)dst,
                                       cursor, dis, csr_src, csr_w);
  reg_csr<<<EB, 256, 0, stream>>>(src, dst, row_off, csr_src,
                                  out + (size_t)NN * 40, E);

  // X -> bf16 table
  cvt_bf16<<<(NN * 128 / 8 + 255) / 256, 256, 0, stream>>>(
      (const float4*)X, (uint2*)Xb, NN * 128 / 8);
  // layer 1: agg(Xb) -> B_agg ; gemm+relu -> H1b (bf16)
  agg128b<<<WB, 256, 0, stream>>>(Xb, dis, row_off, csr_src, csr_w, B_agg);
  gemm128<<<NN / 64, 256, 0, stream>>>(B_agg, W1, b1, nullptr, H1b, 1);
  // layer 2: agg(H1b) -> B_agg ; gemm+relu -> h2 (fp32)
  agg128b<<<WB, 256, 0, stream>>>(H1b, dis, row_off, csr_src, csr_w, B_agg);
  gemm128<<<NN / 64, 256, 0, stream>>>(B_agg, W2, b2, h2, nullptr, 0);
  // layer 3: gemm40(h2) -> G3 ; fused agg + bias + log_softmax -> out
  gemm40<<<WB, 256, 0, stream>>>(h2, W3, G3);
  agg40_softmax<<<WB, 256, 0, stream>>>(G3, dis, row_off, csr_src, csr_w, b3,
                                        out);
}

// Round 5
// 362.878 us; speedup vs baseline: 1.5542x; 1.0429x over previous
//
#include <hip/hip_runtime.h>
#include <hip/hip_bf16.h>
#include <math.h>

#define NN 40000
#define EE 640000

// ---- bf16 helpers ---------------------------------------------------------
__device__ __forceinline__ unsigned bf16rne(float x) {
  unsigned u = __float_as_uint(x);
  return (u + 0x7fffu + ((u >> 16) & 1u)) >> 16;
}
__device__ __forceinline__ unsigned packbf2(float lo, float hi) {
  return bf16rne(lo) | (bf16rne(hi) << 16);
}
__device__ __forceinline__ float bflo(unsigned u) {
  return __uint_as_float(u << 16);
}
__device__ __forceinline__ float bfhi(unsigned u) {
  return __uint_as_float(u & 0xffff0000u);
}

// ---------------------------------------------------------------------------
// in-degree counts; 4 edges per thread (int4), one atomic per edge
// ---------------------------------------------------------------------------
__global__ __launch_bounds__(256) void edge_pass1(
    const int4* __restrict__ dst4, int* __restrict__ cnt) {
  int e = blockIdx.x * 256 + threadIdx.x;
  if (e >= EE / 4) return;
  int4 d = dst4[e];
  atomicAdd(&cnt[d.x], 1);
  atomicAdd(&cnt[d.y], 1);
  atomicAdd(&cnt[d.z], 1);
  atomicAdd(&cnt[d.w], 1);
}

// ---------------------------------------------------------------------------
// single-block chunked scan, fully coalesced (see R3 post-mortem).
// ---------------------------------------------------------------------------
__global__ __launch_bounds__(1024) void scan_kernel(
    const int4* __restrict__ cnt4, int* __restrict__ row_off,
    int* __restrict__ cursor, float* __restrict__ dis) {
  __shared__ int wsum[16];
  __shared__ int btot;
  int t = threadIdx.x;
  int lane = t & 63, w = t >> 6;
  int running = 0;
  for (int c = 0; c < 10; c++) {
    int idx4 = c * 1024 + t;
    bool ok = idx4 * 4 < NN;
    int4 v = ok ? cnt4[idx4] : int4{0, 0, 0, 0};
    int ts = v.x + v.y + v.z + v.w;
    int incl = ts;
#pragma unroll
    for (int off = 1; off < 64; off <<= 1) {
      int u = __shfl_up(incl, off, 64);
      if (lane >= off) incl += u;
    }
    if (lane == 63) wsum[w] = incl;
    __syncthreads();
    if (t < 16) {
      int x = wsum[t];
#pragma unroll
      for (int off = 1; off < 16; off <<= 1) {
        int u = __shfl_up(x, off, 64);
        if (t >= off) x += u;
      }
      wsum[t] = x;
      if (t == 15) btot = x;
    }
    __syncthreads();
    int base = running + (w ? wsum[w - 1] : 0) + (incl - ts);
    if (ok) {
      int4 r;
      r.x = base;
      r.y = base + v.x;
      r.z = r.y + v.y;
      r.w = r.z + v.z;
      ((int4*)row_off)[idx4] = r;
      ((int4*)cursor)[idx4] = r;
      float4 d;
      d.x = rsqrtf((float)(v.x + 1));
      d.y = rsqrtf((float)(v.y + 1));
      d.z = rsqrtf((float)(v.z + 1));
      d.w = rsqrtf((float)(v.w + 1));
      ((float4*)dis)[idx4] = d;
    }
    running += btot;
    __syncthreads();
  }
  if (t == 0) row_off[NN] = running;
}

// ---------------------------------------------------------------------------
// CSR fill: only csr_src now — dis is folded into the gather tables, so
// csr_w (640k scattered stores + 640k dis gathers) is gone.
// ---------------------------------------------------------------------------
__global__ __launch_bounds__(256) void fill_kernel(
    const int4* __restrict__ src4, const int4* __restrict__ dst4,
    int* __restrict__ cursor, int* __restrict__ csr_src) {
  int e = blockIdx.x * 256 + threadIdx.x;
  if (e >= EE / 4) return;
  int4 s = src4[e];
  int4 d = dst4[e];
  int i0 = atomicAdd(&cursor[d.x], 1);
  int i1 = atomicAdd(&cursor[d.y], 1);
  int i2 = atomicAdd(&cursor[d.z], 1);
  int i3 = atomicAdd(&cursor[d.w], 1);
  csr_src[i0] = s.x;
  csr_src[i1] = s.y;
  csr_src[i2] = s.z;
  csr_src[i3] = s.w;
}

// ---------------------------------------------------------------------------
// reg_loss via CSR row scan, masked aligned int4 loads (4 entries / L2
// transaction instead of 1 — R4 showed reg_csr transaction-latency bound).
// ---------------------------------------------------------------------------
__global__ __launch_bounds__(256) void reg_csr(
    const int* __restrict__ src, const int* __restrict__ dst,
    const int* __restrict__ row_off, const int* __restrict__ csr_src,
    float* __restrict__ out_scalar, int E) {
  int e = blockIdx.x * 256 + threadIdx.x;
  int c = 0;
  if (e < E) {
    int i = src[e], j = dst[e];
    int b = row_off[i], en = row_off[i + 1];
    int q0 = b >> 2, q1 = (en + 3) >> 2;  // aligned int4 range (EE mult of 4)
    for (int q = q0; q < q1; q++) {
      int4 v = ((const int4*)csr_src)[q];
      int k = q * 4;
      c += (v.x == j && k + 0 >= b && k + 0 < en);
      c += (v.y == j && k + 1 >= b && k + 1 < en);
      c += (v.z == j && k + 2 >= b && k + 2 < en);
      c += (v.w == j && k + 3 >= b && k + 3 < en);
    }
  }
  float v = (float)c;
  for (int off = 32; off; off >>= 1) v += __shfl_down(v, off, 64);
  __shared__ float ws[4];
  int lane = threadIdx.x & 63, w = threadIdx.x >> 6;
  if (lane == 0) ws[w] = v;
  __syncthreads();
  if (threadIdx.x == 0) atomicAdd(out_scalar, ws[0] + ws[1] + ws[2] + ws[3]);
}

// ---------------------------------------------------------------------------
// fp32 X -> bf16 table scaled by dis[row]: T[s] = dis[s]*X[s]
// ---------------------------------------------------------------------------
__global__ __launch_bounds__(256) void cvt_bf16(const float4* __restrict__ in,
                                                const float* __restrict__ dis,
                                                uint2* __restrict__ outp,
                                                int n8) {
  int i = blockIdx.x * 256 + threadIdx.x;
  if (i >= n8) return;
  float di = dis[i >> 4];  // 16 groups of 8 per 128-wide row
  float4 a = in[i * 2], b = in[i * 2 + 1];
  uint2 o;
  o.x = packbf2(di * a.x, di * a.y);
  o.y = packbf2(di * a.z, di * a.w);
  outp[i * 2] = o;
  uint2 p;
  p.x = packbf2(di * b.x, di * b.y);
  p.y = packbf2(di * b.z, di * b.w);
  outp[i * 2 + 1] = p;
}

// ---------------------------------------------------------------------------
// 128-wide aggregation over pre-scaled bf16 table T[s]=dis[s]*H[s]:
// out[i] = dis[i] * (sum_e T[src_e] + T[i])
// ---------------------------------------------------------------------------
__global__ __launch_bounds__(256) void agg128b(
    const unsigned* __restrict__ Hb, const float* __restrict__ dis,
    const int* __restrict__ row_off, const int* __restrict__ csr_src,
    float* __restrict__ out) {
  int node = __builtin_amdgcn_readfirstlane(blockIdx.x * 4 + (threadIdx.x >> 6));
  int lane = threadIdx.x & 63;
  float di = dis[node];
  unsigned v = Hb[(size_t)node * 64 + lane];
  float a0 = bflo(v), a1 = bfhi(v);
  int beg = row_off[node], end = row_off[node + 1];
  int e = beg;
  for (; e + 4 <= end; e += 4) {
    int s0 = csr_src[e + 0], s1 = csr_src[e + 1];
    int s2 = csr_src[e + 2], s3 = csr_src[e + 3];
    unsigned u0 = Hb[(size_t)s0 * 64 + lane];
    unsigned u1 = Hb[(size_t)s1 * 64 + lane];
    unsigned u2 = Hb[(size_t)s2 * 64 + lane];
    unsigned u3 = Hb[(size_t)s3 * 64 + lane];
    a0 += bflo(u0); a1 += bfhi(u0);
    a0 += bflo(u1); a1 += bfhi(u1);
    a0 += bflo(u2); a1 += bfhi(u2);
    a0 += bflo(u3); a1 += bfhi(u3);
  }
  for (; e < end; e++) {
    unsigned u = Hb[(size_t)csr_src[e] * 64 + lane];
    a0 += bflo(u);
    a1 += bfhi(u);
  }
  float2 o;
  o.x = di * a0;
  o.y = di * a1;
  ((float2*)(out + (size_t)node * 128))[lane] = o;
}

// ---------------------------------------------------------------------------
// fp32 GEMM: out[M x 128] = A[M x 128] @ W[128 x 128] + b, relu.
// outMode 0 -> fp32 out ; 1 -> bf16 out pre-scaled by dis[row] (gather table)
// ---------------------------------------------------------------------------
__global__ __launch_bounds__(256) void gemm128(
    const float* __restrict__ A, const float* __restrict__ W,
    const float* __restrict__ bias, const float* __restrict__ dis,
    float* __restrict__ outF, unsigned* __restrict__ outB, int outMode) {
  __shared__ float XT[64][68];    // [k][row]
  __shared__ float Ws[64][128];   // [k][col]
  int t = threadIdx.x;
  int tx = t & 31, ty = t >> 5;
  int rowBase = blockIdx.x * 64;
  float acc[8][4] = {};
  for (int kt = 0; kt < 128; kt += 64) {
    {
      int kk = (t & 15) * 4;
      int r0 = t >> 4;
      for (int i = 0; i < 4; i++) {
        int r = r0 + i * 16;
        float4 v = *(const float4*)&A[(size_t)(rowBase + r) * 128 + kt + kk];
        XT[kk + 0][r] = v.x;
        XT[kk + 1][r] = v.y;
        XT[kk + 2][r] = v.z;
        XT[kk + 3][r] = v.w;
      }
    }
    {
      int c4 = (t & 31) * 4;
      int kr = t >> 5;
      for (int i = 0; i < 8; i++) {
        int k = kr + i * 8;
        *(float4*)&Ws[k][c4] = *(const float4*)&W[(size_t)(kt + k) * 128 + c4];
      }
    }
    __syncthreads();
#pragma unroll 8
    for (int k = 0; k < 64; k++) {
      float a[8];
      *(float4*)&a[0] = *(const float4*)&XT[k][ty * 8];
      *(float4*)&a[4] = *(const float4*)&XT[k][ty * 8 + 4];
      float4 b = *(const float4*)&Ws[k][tx * 4];
#pragma unroll
      for (int i = 0; i < 8; i++) {
        acc[i][0] += a[i] * b.x;
        acc[i][1] += a[i] * b.y;
        acc[i][2] += a[i] * b.z;
        acc[i][3] += a[i] * b.w;
      }
    }
    __syncthreads();
  }
  float4 bv = *(const float4*)&bias[tx * 4];
  for (int i = 0; i < 8; i++) {
    int r = rowBase + ty * 8 + i;
    float x0 = fmaxf(acc[i][0] + bv.x, 0.f);
    float x1 = fmaxf(acc[i][1] + bv.y, 0.f);
    float x2 = fmaxf(acc[i][2] + bv.z, 0.f);
    float x3 = fmaxf(acc[i][3] + bv.w, 0.f);
    if (outMode == 0) {
      float4 o = {x0, x1, x2, x3};
      *(float4*)&outF[(size_t)r * 128 + tx * 4] = o;
    } else {
      float di = dis[r];
      uint2 o;
      o.x = packbf2(di * x0, di * x1);
      o.y = packbf2(di * x2, di * x3);
      *(uint2*)&outB[(size_t)r * 64 + tx * 2] = o;
    }
  }
}

// ---------------------------------------------------------------------------
// GEMM 128 -> 40 (no bias): one wave per row, W3 in LDS; output scaled by
// dis[node] (pre-scaled gather table for agg40_softmax)
// ---------------------------------------------------------------------------
__global__ __launch_bounds__(256) void gemm40(const float* __restrict__ A,
                                              const float* __restrict__ W3,
                                              const float* __restrict__ dis,
                                              float* __restrict__ G) {
  __shared__ float Ws[128 * 40];
  int t = threadIdx.x;
  for (int i = t; i < 128 * 40; i += 256) Ws[i] = W3[i];
  __syncthreads();
  int node = __builtin_amdgcn_readfirstlane(blockIdx.x * 4 + (t >> 6));
  int lane = t & 63;
  int cl = lane < 40 ? lane : 39;
  const float* arow = A + (size_t)node * 128;
  float acc = 0.f;
#pragma unroll 8
  for (int k = 0; k < 128; k++) acc += arow[k] * Ws[k * 40 + cl];
  if (lane < 40) G[(size_t)node * 40 + lane] = dis[node] * acc;
}

// ---------------------------------------------------------------------------
// fused: 40-wide aggregation of pre-scaled T + bias + log_softmax -> d_out
// ---------------------------------------------------------------------------
__global__ __launch_bounds__(256) void agg40_softmax(
    const float* __restrict__ G, const float* __restrict__ dis,
    const int* __restrict__ row_off, const int* __restrict__ csr_src,
    const float* __restrict__ b3, float* __restrict__ outp) {
  int node = __builtin_amdgcn_readfirstlane(blockIdx.x * 4 + (threadIdx.x >> 6));
  int lane = threadIdx.x & 63;
  int cl = lane < 40 ? lane : 39;
  float di = dis[node];
  float a = G[(size_t)node * 40 + cl];
  int beg = row_off[node], end = row_off[node + 1];
  int e = beg;
  for (; e + 4 <= end; e += 4) {
    int s0 = csr_src[e + 0], s1 = csr_src[e + 1];
    int s2 = csr_src[e + 2], s3 = csr_src[e + 3];
    a += G[(size_t)s0 * 40 + cl];
    a += G[(size_t)s1 * 40 + cl];
    a += G[(size_t)s2 * 40 + cl];
    a += G[(size_t)s3 * 40 + cl];
  }
  for (; e < end; e++) {
    a += G[(size_t)csr_src[e] * 40 + cl];
  }
  float o = di * a + b3[cl];
  float m = (lane < 40) ? o : -1e30f;
  for (int off = 32; off; off >>= 1) m = fmaxf(m, __shfl_xor(m, off, 64));
  float ex = (lane < 40) ? expf(o - m) : 0.f;
  float ssum = ex;
  for (int off = 32; off; off >>= 1) ssum += __shfl_xor(ssum, off, 64);
  float res = o - m - logf(ssum);
  if (lane < 40) outp[(size_t)node * 40 + lane] = res;
}

// ---------------------------------------------------------------------------
extern "C" void kernel_launch(void* const* d_in, const int* in_sizes, int n_in,
                              void* d_out, int out_size, void* d_ws,
                              size_t ws_size, hipStream_t stream) {
  const float* X = (const float*)d_in[0];
  const int* ei = (const int*)d_in[1];
  const float* W1 = (const float*)d_in[2];
  const float* b1 = (const float*)d_in[3];
  const float* W2 = (const float*)d_in[4];
  const float* b2 = (const float*)d_in[5];
  const float* W3 = (const float*)d_in[6];
  const float* b3 = (const float*)d_in[7];
  float* out = (float*)d_out;

  const int E = EE;
  const int* src = ei;
  const int* dst = ei + E;

  char* w = (char*)d_ws;
  auto carve = [&](size_t bytes) {
    char* p = w;
    w += (bytes + 255) & ~(size_t)255;
    return p;
  };
  int* cnt = (int*)carve(NN * 4);
  float* dis = (float*)carve(NN * 4);
  int* row_off = (int*)carve((NN + 1) * 4);
  int* cursor = (int*)carve(NN * 4);
  int* csr_src = (int*)carve((size_t)EE * 4);
  float* B_agg = (float*)carve((size_t)NN * 128 * 4);       // 20.5 MB
  char* blk = carve((size_t)NN * 128 * 4);                  // 20.5 MB shared
  unsigned* Xb = (unsigned*)blk;                            // bf16 T(X)
  unsigned* H1b = (unsigned*)(blk + (size_t)NN * 128 * 2);  // bf16 T(h1)
  float* h2 = (float*)blk;   // layer-2 out, alias (Xb,H1b dead by then)
  float* G3 = B_agg;         // layer-3 pre-agg, alias (B_agg dead by then)

  hipMemsetAsync(cnt, 0, NN * 4, stream);
  hipMemsetAsync((char*)d_out + (size_t)NN * 40 * 4, 0, 4, stream);

  const int E4B = (EE / 4 + 255) / 256;  // 625
  const int EB = (EE + 255) / 256;       // 2500
  const int WB = NN / 4;                 // 10000

  edge_pass1<<<E4B, 256, 0, stream>>>((const int4*)dst, cnt);
  scan_kernel<<<1, 1024, 0, stream>>>((const int4*)cnt, row_off, cursor, dis);
  fill_kernel<<<E4B, 256, 0, stream>>>((const int4*)src, (const int4*)dst,
                                       cursor, csr_src);
  reg_csr<<<EB, 256, 0, stream>>>(src, dst, row_off, csr_src,
                                  out + (size_t)NN * 40, E);

  cvt_bf16<<<(NN * 128 / 8 + 255) / 256, 256, 0, stream>>>(
      (const float4*)X, dis, (uint2*)Xb, NN * 128 / 8);
  // layer 1: agg(T(X)) -> B_agg ; gemm+relu -> T(h1) bf16
  agg128b<<<WB, 256, 0, stream>>>(Xb, dis, row_off, csr_src, B_agg);
  gemm128<<<NN / 64, 256, 0, stream>>>(B_agg, W1, b1, dis, nullptr, H1b, 1);
  // layer 2: agg(T(h1)) -> B_agg ; gemm+relu -> h2 fp32
  agg128b<<<WB, 256, 0, stream>>>(H1b, dis, row_off, csr_src, B_agg);
  gemm128<<<NN / 64, 256, 0, stream>>>(B_agg, W2, b2, dis, h2, nullptr, 0);
  // layer 3: gemm40(h2)*dis -> G3 ; fused agg + bias + log_softmax -> out
  gemm40<<<WB, 256, 0, stream>>>(h2, W3, dis, G3);
  agg40_softmax<<<WB, 256, 0, stream>>>(G3, dis, row_off, csr_src, b3, out);
}

// Round 6
// 345.688 us; speedup vs baseline: 1.6315x; 1.0497x over previous
//
#include <hip/hip_runtime.h>
#include <hip/hip_bf16.h>
#include <math.h>

#define NN 40000
#define EE 640000
#define MPAD 40064           // NN rounded up to 128 for MFMA tile staging
#define LDS_STRIDE 136       // bf16 elems per LDS row (128 + 8 pad)

typedef short bf16x8 __attribute__((ext_vector_type(8)));
typedef float f32x16 __attribute__((ext_vector_type(16)));

// ---- bf16 helpers ---------------------------------------------------------
__device__ __forceinline__ unsigned bf16rne(float x) {
  unsigned u = __float_as_uint(x);
  return (u + 0x7fffu + ((u >> 16) & 1u)) >> 16;
}
__device__ __forceinline__ unsigned packbf2(float lo, float hi) {
  return bf16rne(lo) | (bf16rne(hi) << 16);
}
__device__ __forceinline__ float bflo(unsigned u) {
  return __uint_as_float(u << 16);
}
__device__ __forceinline__ float bfhi(unsigned u) {
  return __uint_as_float(u & 0xffff0000u);
}

// ---------------------------------------------------------------------------
// in-degree counts; 4 edges per thread (int4), one atomic per edge
// ---------------------------------------------------------------------------
__global__ __launch_bounds__(256) void edge_pass1(
    const int4* __restrict__ dst4, int* __restrict__ cnt) {
  int e = blockIdx.x * 256 + threadIdx.x;
  if (e >= EE / 4) return;
  int4 d = dst4[e];
  atomicAdd(&cnt[d.x], 1);
  atomicAdd(&cnt[d.y], 1);
  atomicAdd(&cnt[d.z], 1);
  atomicAdd(&cnt[d.w], 1);
}

// ---------------------------------------------------------------------------
// single-block chunked scan, fully coalesced (see R3 post-mortem).
// ---------------------------------------------------------------------------
__global__ __launch_bounds__(1024) void scan_kernel(
    const int4* __restrict__ cnt4, int* __restrict__ row_off,
    int* __restrict__ cursor, float* __restrict__ dis) {
  __shared__ int wsum[16];
  __shared__ int btot;
  int t = threadIdx.x;
  int lane = t & 63, w = t >> 6;
  int running = 0;
  for (int c = 0; c < 10; c++) {
    int idx4 = c * 1024 + t;
    bool ok = idx4 * 4 < NN;
    int4 v = ok ? cnt4[idx4] : int4{0, 0, 0, 0};
    int ts = v.x + v.y + v.z + v.w;
    int incl = ts;
#pragma unroll
    for (int off = 1; off < 64; off <<= 1) {
      int u = __shfl_up(incl, off, 64);
      if (lane >= off) incl += u;
    }
    if (lane == 63) wsum[w] = incl;
    __syncthreads();
    if (t < 16) {
      int x = wsum[t];
#pragma unroll
      for (int off = 1; off < 16; off <<= 1) {
        int u = __shfl_up(x, off, 64);
        if (t >= off) x += u;
      }
      wsum[t] = x;
      if (t == 15) btot = x;
    }
    __syncthreads();
    int base = running + (w ? wsum[w - 1] : 0) + (incl - ts);
    if (ok) {
      int4 r;
      r.x = base;
      r.y = base + v.x;
      r.z = r.y + v.y;
      r.w = r.z + v.z;
      ((int4*)row_off)[idx4] = r;
      ((int4*)cursor)[idx4] = r;
      float4 d;
      d.x = rsqrtf((float)(v.x + 1));
      d.y = rsqrtf((float)(v.y + 1));
      d.z = rsqrtf((float)(v.z + 1));
      d.w = rsqrtf((float)(v.w + 1));
      ((float4*)dis)[idx4] = d;
    }
    running += btot;
    __syncthreads();
  }
  if (t == 0) row_off[NN] = running;
}

// ---------------------------------------------------------------------------
// CSR fill (csr_src only; dis folded into gather tables)
// ---------------------------------------------------------------------------
__global__ __launch_bounds__(256) void fill_kernel(
    const int4* __restrict__ src4, const int4* __restrict__ dst4,
    int* __restrict__ cursor, int* __restrict__ csr_src) {
  int e = blockIdx.x * 256 + threadIdx.x;
  if (e >= EE / 4) return;
  int4 s = src4[e];
  int4 d = dst4[e];
  int i0 = atomicAdd(&cursor[d.x], 1);
  int i1 = atomicAdd(&cursor[d.y], 1);
  int i2 = atomicAdd(&cursor[d.z], 1);
  int i3 = atomicAdd(&cursor[d.w], 1);
  csr_src[i0] = s.x;
  csr_src[i1] = s.y;
  csr_src[i2] = s.z;
  csr_src[i3] = s.w;
}

// ---------------------------------------------------------------------------
// reg_loss via CSR row scan, masked aligned int4 loads
// ---------------------------------------------------------------------------
__global__ __launch_bounds__(256) void reg_csr(
    const int* __restrict__ src, const int* __restrict__ dst,
    const int* __restrict__ row_off, const int* __restrict__ csr_src,
    float* __restrict__ out_scalar, int E) {
  int e = blockIdx.x * 256 + threadIdx.x;
  int c = 0;
  if (e < E) {
    int i = src[e], j = dst[e];
    int b = row_off[i], en = row_off[i + 1];
    int q0 = b >> 2, q1 = (en + 3) >> 2;
    for (int q = q0; q < q1; q++) {
      int4 v = ((const int4*)csr_src)[q];
      int k = q * 4;
      c += (v.x == j && k + 0 >= b && k + 0 < en);
      c += (v.y == j && k + 1 >= b && k + 1 < en);
      c += (v.z == j && k + 2 >= b && k + 2 < en);
      c += (v.w == j && k + 3 >= b && k + 3 < en);
    }
  }
  float v = (float)c;
  for (int off = 32; off; off >>= 1) v += __shfl_down(v, off, 64);
  __shared__ float ws[4];
  int lane = threadIdx.x & 63, w = threadIdx.x >> 6;
  if (lane == 0) ws[w] = v;
  __syncthreads();
  if (threadIdx.x == 0) atomicAdd(out_scalar, ws[0] + ws[1] + ws[2] + ws[3]);
}

// ---------------------------------------------------------------------------
// fp32 X -> bf16 table scaled by dis[row]: T[s] = dis[s]*X[s]
// ---------------------------------------------------------------------------
__global__ __launch_bounds__(256) void cvt_bf16(const float4* __restrict__ in,
                                                const float* __restrict__ dis,
                                                uint2* __restrict__ outp,
                                                int n8) {
  int i = blockIdx.x * 256 + threadIdx.x;
  if (i >= n8) return;
  float di = dis[i >> 4];
  float4 a = in[i * 2], b = in[i * 2 + 1];
  uint2 o;
  o.x = packbf2(di * a.x, di * a.y);
  o.y = packbf2(di * a.z, di * a.w);
  outp[i * 2] = o;
  uint2 p;
  p.x = packbf2(di * b.x, di * b.y);
  p.y = packbf2(di * b.z, di * b.w);
  outp[i * 2 + 1] = p;
}

// ---------------------------------------------------------------------------
// W[k][n] fp32 -> Wt[n][k] bf16 (once per layer; feeds MFMA B-operand)
// block = 128 threads = one output row n; gridDim 256 covers W1+W2
// ---------------------------------------------------------------------------
__global__ __launch_bounds__(128) void cvt_wt(const float* __restrict__ W1,
                                              const float* __restrict__ W2,
                                              unsigned short* __restrict__ Wt1,
                                              unsigned short* __restrict__ Wt2) {
  int n = blockIdx.x & 127;
  const float* W = (blockIdx.x < 128) ? W1 : W2;
  unsigned short* Wt = (blockIdx.x < 128) ? Wt1 : Wt2;
  int k = threadIdx.x;
  Wt[n * 128 + k] = (unsigned short)bf16rne(W[k * 128 + n]);
}

// ---------------------------------------------------------------------------
// 128-wide aggregation over pre-scaled bf16 table, bf16 packed OUTPUT:
// out[i] = bf16( dis[i] * (sum_e T[src_e] + T[i]) )   -- MFMA A-operand table
// ---------------------------------------------------------------------------
__global__ __launch_bounds__(256) void agg128b(
    const unsigned* __restrict__ Hb, const float* __restrict__ dis,
    const int* __restrict__ row_off, const int* __restrict__ csr_src,
    unsigned* __restrict__ outB) {
  int node = __builtin_amdgcn_readfirstlane(blockIdx.x * 4 + (threadIdx.x >> 6));
  int lane = threadIdx.x & 63;
  float di = dis[node];
  unsigned v = Hb[(size_t)node * 64 + lane];
  float a0 = bflo(v), a1 = bfhi(v);
  int beg = row_off[node], end = row_off[node + 1];
  int e = beg;
  for (; e + 4 <= end; e += 4) {
    int s0 = csr_src[e + 0], s1 = csr_src[e + 1];
    int s2 = csr_src[e + 2], s3 = csr_src[e + 3];
    unsigned u0 = Hb[(size_t)s0 * 64 + lane];
    unsigned u1 = Hb[(size_t)s1 * 64 + lane];
    unsigned u2 = Hb[(size_t)s2 * 64 + lane];
    unsigned u3 = Hb[(size_t)s3 * 64 + lane];
    a0 += bflo(u0); a1 += bfhi(u0);
    a0 += bflo(u1); a1 += bfhi(u1);
    a0 += bflo(u2); a1 += bfhi(u2);
    a0 += bflo(u3); a1 += bfhi(u3);
  }
  for (; e < end; e++) {
    unsigned u = Hb[(size_t)csr_src[e] * 64 + lane];
    a0 += bflo(u);
    a1 += bfhi(u);
  }
  outB[(size_t)node * 64 + lane] = packbf2(di * a0, di * a1);
}

// ---------------------------------------------------------------------------
// MFMA bf16 GEMM: out[Mtile=128 x 128] = relu(A @ W + b)
// A: [MPAD][128] bf16 packed rows. Wt: [128][128] bf16, [n][k] layout.
// outMode 0 -> fp32 out ; 1 -> bf16 out scaled by dis[row] (gather table)
// 4 waves x (32-row strip); per wave 4 n-tiles x 8 k-steps of 32x32x16.
// C/D layout: col=lane&31, row=(reg&3)+8*(reg>>2)+4*(lane>>5) [m74/m101]
// ---------------------------------------------------------------------------
__global__ __launch_bounds__(256) void gemm_mfma(
    const unsigned* __restrict__ Ab, const unsigned* __restrict__ Wt,
    const float* __restrict__ bias, const float* __restrict__ dis,
    float* __restrict__ outF, unsigned short* __restrict__ outB, int outMode) {
  __shared__ unsigned short At[128 * LDS_STRIDE];
  __shared__ unsigned short Bt[128 * LDS_STRIDE];
  int t = threadIdx.x;
  int rowBase = blockIdx.x * 128;
  {
    const uint4* ga = (const uint4*)(Ab + (size_t)rowBase * 64);
    const uint4* gw = (const uint4*)Wt;
#pragma unroll
    for (int i = 0; i < 8; i++) {
      int idx = i * 256 + t;           // uint4 index over 128x16
      int r = idx >> 4, c = idx & 15;  // c in 8-bf16 units
      uint4 va = ga[idx];
      uint4 vw = gw[idx];
      *(uint4*)&At[r * LDS_STRIDE + c * 8] = va;
      *(uint4*)&Bt[r * LDS_STRIDE + c * 8] = vw;
    }
  }
  __syncthreads();
  int lane = t & 63, w = t >> 6;
  int m31 = lane & 31;
  int khalf = (lane >> 5) * 8;
  f32x16 acc[4] = {};
#pragma unroll
  for (int ks = 0; ks < 8; ks++) {
    bf16x8 a = *(bf16x8*)&At[(w * 32 + m31) * LDS_STRIDE + ks * 16 + khalf];
#pragma unroll
    for (int nt = 0; nt < 4; nt++) {
      bf16x8 b = *(bf16x8*)&Bt[(nt * 32 + m31) * LDS_STRIDE + ks * 16 + khalf];
      acc[nt] = __builtin_amdgcn_mfma_f32_32x32x16_bf16(a, b, acc[nt], 0, 0, 0);
    }
  }
  int rsel = (lane >> 5) * 4;
#pragma unroll
  for (int nt = 0; nt < 4; nt++) {
    int col = nt * 32 + m31;
    float bv = bias[col];
#pragma unroll
    for (int r = 0; r < 16; r++) {
      int row = rowBase + w * 32 + (r & 3) + 8 * (r >> 2) + rsel;
      if (row < NN) {
        float x = fmaxf(acc[nt][r] + bv, 0.f);
        if (outMode == 0) {
          outF[(size_t)row * 128 + col] = x;
        } else {
          outB[(size_t)row * 128 + col] = (unsigned short)bf16rne(dis[row] * x);
        }
      }
    }
  }
}

// ---------------------------------------------------------------------------
// GEMM 128 -> 40 (no bias): one wave per row, W3 in LDS; output scaled by
// dis[node] (pre-scaled gather table for agg40_softmax)
// ---------------------------------------------------------------------------
__global__ __launch_bounds__(256) void gemm40(const float* __restrict__ A,
                                              const float* __restrict__ W3,
                                              const float* __restrict__ dis,
                                              float* __restrict__ G) {
  __shared__ float Ws[128 * 40];
  int t = threadIdx.x;
  for (int i = t; i < 128 * 40; i += 256) Ws[i] = W3[i];
  __syncthreads();
  int node = __builtin_amdgcn_readfirstlane(blockIdx.x * 4 + (t >> 6));
  int lane = t & 63;
  int cl = lane < 40 ? lane : 39;
  const float* arow = A + (size_t)node * 128;
  float acc = 0.f;
#pragma unroll 8
  for (int k = 0; k < 128; k++) acc += arow[k] * Ws[k * 40 + cl];
  if (lane < 40) G[(size_t)node * 40 + lane] = dis[node] * acc;
}

// ---------------------------------------------------------------------------
// fused: 40-wide aggregation of pre-scaled T + bias + log_softmax -> d_out
// ---------------------------------------------------------------------------
__global__ __launch_bounds__(256) void agg40_softmax(
    const float* __restrict__ G, const float* __restrict__ dis,
    const int* __restrict__ row_off, const int* __restrict__ csr_src,
    const float* __restrict__ b3, float* __restrict__ outp) {
  int node = __builtin_amdgcn_readfirstlane(blockIdx.x * 4 + (threadIdx.x >> 6));
  int lane = threadIdx.x & 63;
  int cl = lane < 40 ? lane : 39;
  float di = dis[node];
  float a = G[(size_t)node * 40 + cl];
  int beg = row_off[node], end = row_off[node + 1];
  int e = beg;
  for (; e + 4 <= end; e += 4) {
    int s0 = csr_src[e + 0], s1 = csr_src[e + 1];
    int s2 = csr_src[e + 2], s3 = csr_src[e + 3];
    a += G[(size_t)s0 * 40 + cl];
    a += G[(size_t)s1 * 40 + cl];
    a += G[(size_t)s2 * 40 + cl];
    a += G[(size_t)s3 * 40 + cl];
  }
  for (; e < end; e++) {
    a += G[(size_t)csr_src[e] * 40 + cl];
  }
  float o = di * a + b3[cl];
  float m = (lane < 40) ? o : -1e30f;
  for (int off = 32; off; off >>= 1) m = fmaxf(m, __shfl_xor(m, off, 64));
  float ex = (lane < 40) ? expf(o - m) : 0.f;
  float ssum = ex;
  for (int off = 32; off; off >>= 1) ssum += __shfl_xor(ssum, off, 64);
  float res = o - m - logf(ssum);
  if (lane < 40) outp[(size_t)node * 40 + lane] = res;
}

// ---------------------------------------------------------------------------
extern "C" void kernel_launch(void* const* d_in, const int* in_sizes, int n_in,
                              void* d_out, int out_size, void* d_ws,
                              size_t ws_size, hipStream_t stream) {
  const float* X = (const float*)d_in[0];
  const int* ei = (const int*)d_in[1];
  const float* W1 = (const float*)d_in[2];
  const float* b1 = (const float*)d_in[3];
  const float* W2 = (const float*)d_in[4];
  const float* b2 = (const float*)d_in[5];
  const float* W3 = (const float*)d_in[6];
  const float* b3 = (const float*)d_in[7];
  float* out = (float*)d_out;

  const int E = EE;
  const int* src = ei;
  const int* dst = ei + E;

  char* w = (char*)d_ws;
  auto carve = [&](size_t bytes) {
    char* p = w;
    w += (bytes + 255) & ~(size_t)255;
    return p;
  };
  int* cnt = (int*)carve(NN * 4);
  float* dis = (float*)carve(NN * 4);
  int* row_off = (int*)carve((NN + 1) * 4);
  int* cursor = (int*)carve(NN * 4);
  int* csr_src = (int*)carve((size_t)EE * 4);
  unsigned short* Wt1 = (unsigned short*)carve(128 * 128 * 2);
  unsigned short* Wt2 = (unsigned short*)carve(128 * 128 * 2);
  unsigned* Ab = (unsigned*)carve((size_t)MPAD * 128 * 2);  // 10.26 MB, padded
  char* blk = carve((size_t)NN * 128 * 4);                  // 20.5 MB shared
  unsigned* Xb = (unsigned*)blk;                            // bf16 T(X)
  unsigned* H1b = (unsigned*)(blk + (size_t)NN * 128 * 2);  // bf16 T(h1)
  float* h2 = (float*)blk;   // layer-2 fp32 out, alias (Xb,H1b dead by then)
  float* G3 = (float*)Ab;    // layer-3 pre-agg, alias (Ab dead after gemm2)

  hipMemsetAsync(cnt, 0, NN * 4, stream);
  hipMemsetAsync((char*)d_out + (size_t)NN * 40 * 4, 0, 4, stream);

  const int E4B = (EE / 4 + 255) / 256;  // 625
  const int EB = (EE + 255) / 256;       // 2500
  const int WB = NN / 4;                 // 10000
  const int GB = MPAD / 128;             // 313 MFMA gemm blocks

  edge_pass1<<<E4B, 256, 0, stream>>>((const int4*)dst, cnt);
  scan_kernel<<<1, 1024, 0, stream>>>((const int4*)cnt, row_off, cursor, dis);
  fill_kernel<<<E4B, 256, 0, stream>>>((const int4*)src, (const int4*)dst,
                                       cursor, csr_src);
  reg_csr<<<EB, 256, 0, stream>>>(src, dst, row_off, csr_src,
                                  out + (size_t)NN * 40, E);

  cvt_wt<<<256, 128, 0, stream>>>(W1, W2, Wt1, Wt2);
  cvt_bf16<<<(NN * 128 / 8 + 255) / 256, 256, 0, stream>>>(
      (const float4*)X, dis, (uint2*)Xb, NN * 128 / 8);
  // layer 1: agg(T(X)) -> Ab bf16 ; MFMA gemm+relu -> T(h1) bf16
  agg128b<<<WB, 256, 0, stream>>>(Xb, dis, row_off, csr_src, Ab);
  gemm_mfma<<<GB, 256, 0, stream>>>(Ab, (const unsigned*)Wt1, b1, dis, nullptr,
                                    (unsigned short*)H1b, 1);
  // layer 2: agg(T(h1)) -> Ab bf16 ; MFMA gemm+relu -> h2 fp32
  agg128b<<<WB, 256, 0, stream>>>(H1b, dis, row_off, csr_src, Ab);
  gemm_mfma<<<GB, 256, 0, stream>>>(Ab, (const unsigned*)Wt2, b2, dis, h2,
                                    nullptr, 0);
  // layer 3: gemm40(h2)*dis -> G3 ; fused agg + bias + log_softmax -> out
  gemm40<<<WB, 256, 0, stream>>>(h2, W3, dis, G3);
  agg40_softmax<<<WB, 256, 0, stream>>>(G3, dis, row_off, csr_src, b3, out);
}